// Round 1
// baseline (1975.945 us; speedup 1.0000x reference)
//
#include <hip/hip_runtime.h>

#define HID 128
#define SCAN_CHUNK 1024
#define POOL_CHUNK 512

// ---------------- utility: zero int/float buffers ----------------
__global__ void k_zero32(int* __restrict__ p, int n) {
  int i = blockIdx.x * blockDim.x + threadIdx.x;
  int stride = gridDim.x * blockDim.x;
  for (; i < n; i += stride) p[i] = 0;
}

// ---------------- degree count (int atomics, deterministic) ----------------
__global__ void k_count_deg(const int* __restrict__ dst, int E, int* __restrict__ deg) {
  int i = blockIdx.x * blockDim.x + threadIdx.x;
  int stride = gridDim.x * blockDim.x;
  for (; i < E; i += stride) atomicAdd(&deg[dst[i]], 1);
}

__global__ void k_dinv(const int* __restrict__ deg, float* __restrict__ dinv, int N) {
  int i = blockIdx.x * blockDim.x + threadIdx.x;
  int stride = gridDim.x * blockDim.x;
  for (; i < N; i += stride) dinv[i] = rsqrtf((float)(deg[i] + 1)); // +1 = self loop
}

// ---------------- exclusive scan of deg -> rowstart (3 kernels) ----------------
__global__ void k_scan_block_sums(const int* __restrict__ deg, int N, int* __restrict__ bsum) {
  __shared__ int sh[256];
  int base = blockIdx.x * SCAN_CHUNK;
  int t = threadIdx.x;
  int s = 0;
#pragma unroll
  for (int j = 0; j < 4; ++j) {
    int idx = base + t * 4 + j;
    if (idx < N) s += deg[idx];
  }
  sh[t] = s;
  __syncthreads();
  for (int off = 128; off > 0; off >>= 1) {
    if (t < off) sh[t] += sh[t + off];
    __syncthreads();
  }
  if (t == 0) bsum[blockIdx.x] = sh[0];
}

__global__ void k_scan_offsets(const int* __restrict__ bsum, int nb, int* __restrict__ boff) {
  if (blockIdx.x == 0 && threadIdx.x == 0) {
    int run = 0;
    for (int i = 0; i < nb; ++i) { boff[i] = run; run += bsum[i]; }
  }
}

__global__ void k_scan_write(const int* __restrict__ deg, int N,
                             const int* __restrict__ boff, int* __restrict__ rowstart) {
  __shared__ int sh[256];
  int base = blockIdx.x * SCAN_CHUNK;
  int t = threadIdx.x;
  int v[4];
  int s = 0;
#pragma unroll
  for (int j = 0; j < 4; ++j) {
    int idx = base + t * 4 + j;
    v[j] = (idx < N) ? deg[idx] : 0;
    s += v[j];
  }
  sh[t] = s;
  __syncthreads();
  // Hillis-Steele inclusive scan over 256 thread sums
  for (int off = 1; off < 256; off <<= 1) {
    int x = 0;
    if (t >= off) x = sh[t - off];
    __syncthreads();
    sh[t] += x;
    __syncthreads();
  }
  int excl = sh[t] - s;
  int run = boff[blockIdx.x] + excl;
#pragma unroll
  for (int j = 0; j < 4; ++j) {
    int idx = base + t * 4 + j;
    if (idx < N) rowstart[idx] = run;
    run += v[j];
  }
}

__global__ void k_fill_csr(const int* __restrict__ src, const int* __restrict__ dst, int E,
                           const int* __restrict__ rowstart, int* __restrict__ cursor,
                           int* __restrict__ csr) {
  int i = blockIdx.x * blockDim.x + threadIdx.x;
  int stride = gridDim.x * blockDim.x;
  for (; i < E; i += stride) {
    int d = dst[i];
    int pos = rowstart[d] + atomicAdd(&cursor[d], 1);
    csr[pos] = src[i];
  }
}

// ---------------- dense GEMM: C[N][128] = A[N][K] @ W[K][128] ----------------
// block = 256 threads, tile = 32 rows x 128 cols, K-tile = 32
__global__ __launch_bounds__(256) void k_gemm(const float* __restrict__ A,
                                              const float* __restrict__ W,
                                              float* __restrict__ C, int N, int K) {
  __shared__ float As[32][33];
  __shared__ float Ws[32][128];
  int t = threadIdx.x;
  int tx = t & 31;   // column quad (c = tx*4)
  int ty = t >> 5;   // 0..7 row group
  int r0 = blockIdx.x * 32;
  float4 acc[4];
#pragma unroll
  for (int r = 0; r < 4; ++r) acc[r] = make_float4(0.f, 0.f, 0.f, 0.f);

  int lr = t >> 3;        // 0..31: A-tile load row
  int lk = (t & 7) * 4;   // 0..28: A-tile load k-quad

  for (int kt = 0; kt < K; kt += 32) {
    // A tile 32x32 (zero-padded)
    {
      int gr = r0 + lr;
      float4 av = make_float4(0.f, 0.f, 0.f, 0.f);
      if (gr < N) {
        int kb = kt + lk;
        if (kb + 3 < K) {
          av = *(const float4*)&A[(long)gr * K + kb];
        } else {
          float tmp[4] = {0.f, 0.f, 0.f, 0.f};
          for (int j = 0; j < 4; ++j)
            if (kb + j < K) tmp[j] = A[(long)gr * K + kb + j];
          av = make_float4(tmp[0], tmp[1], tmp[2], tmp[3]);
        }
      }
      As[lr][lk + 0] = av.x; As[lr][lk + 1] = av.y;
      As[lr][lk + 2] = av.z; As[lr][lk + 3] = av.w;
    }
    // W tile 32x128 (zero-padded rows past K)
#pragma unroll
    for (int i = 0; i < 4; ++i) {
      int wr = i * 8 + ty;
      int gk = kt + wr;
      float4 wv = make_float4(0.f, 0.f, 0.f, 0.f);
      if (gk < K) wv = *(const float4*)&W[(long)gk * HID + tx * 4];
      *(float4*)&Ws[wr][tx * 4] = wv;
    }
    __syncthreads();
#pragma unroll
    for (int kk = 0; kk < 32; ++kk) {
      float4 wv = *(float4*)&Ws[kk][tx * 4];
#pragma unroll
      for (int r = 0; r < 4; ++r) {
        float a = As[r * 8 + ty][kk];
        acc[r].x += a * wv.x; acc[r].y += a * wv.y;
        acc[r].z += a * wv.z; acc[r].w += a * wv.w;
      }
    }
    __syncthreads();
  }
#pragma unroll
  for (int r = 0; r < 4; ++r) {
    int gr = r0 + r * 8 + ty;
    if (gr < N) *(float4*)&C[(long)gr * HID + tx * 4] = acc[r];
  }
}

// ---------------- pull aggregation + bias + relu ----------------
// out[i][c] = relu( dinv[i]*( dinv[i]*T[i][c] + sum_nbr dinv[s]*T[s][c] ) + b[c] )
__global__ __launch_bounds__(128) void k_agg(const float* __restrict__ T,
                                             const float* __restrict__ dinv,
                                             const int* __restrict__ rowstart,
                                             const int* __restrict__ deg,
                                             const int* __restrict__ csr,
                                             const float* __restrict__ bias,
                                             float* __restrict__ out, int N) {
  int i = blockIdx.x;
  if (i >= N) return;
  int c = threadIdx.x;
  float di = dinv[i];
  float acc = di * T[(long)i * HID + c];  // self loop (x di again below)
  int s0 = rowstart[i];
  int d = deg[i];
  int j = 0;
  for (; j + 1 < d; j += 2) {
    int s1 = csr[s0 + j];
    int s2 = csr[s0 + j + 1];
    float d1 = dinv[s1];
    float d2 = dinv[s2];
    acc += d1 * T[(long)s1 * HID + c] + d2 * T[(long)s2 * HID + c];
  }
  if (j < d) {
    int s = csr[s0 + j];
    acc += dinv[s] * T[(long)s * HID + c];
  }
  float v = di * acc + bias[c];
  out[(long)i * HID + c] = fmaxf(v, 0.f);
}

// ---------------- graph-size counts ----------------
__global__ void k_cnt(const int* __restrict__ batch, int N, int* __restrict__ cnt) {
  int i = blockIdx.x * blockDim.x + threadIdx.x;
  int stride = gridDim.x * blockDim.x;
  for (; i < N; i += stride) atomicAdd(&cnt[batch[i]], 1);
}

// ---------------- mean-pool partial sums (batch is sorted) ----------------
__global__ __launch_bounds__(128) void k_pool(const float* __restrict__ h,
                                              const int* __restrict__ batch,
                                              float* __restrict__ psum, int N) {
  __shared__ int bsh[POOL_CHUNK];
  int c = threadIdx.x;
  int start = blockIdx.x * POOL_CHUNK;
  int end = min(N, start + POOL_CHUNK);
  int len = end - start;
  if (len <= 0) return;
  for (int i = c; i < len; i += 128) bsh[i] = batch[start + i];
  __syncthreads();
  int cur = bsh[0];
  float acc = 0.f;
  for (int i = 0; i < len; ++i) {
    int g = bsh[i];
    if (g != cur) {
      atomicAdd(&psum[cur * HID + c], acc);
      acc = 0.f;
      cur = g;
    }
    acc += h[(long)(start + i) * HID + c];
  }
  atomicAdd(&psum[cur * HID + c], acc);
}

// ---------------- MLP head: one block per graph ----------------
__global__ __launch_bounds__(128) void k_head(const float* __restrict__ psum,
                                              const int* __restrict__ cnt,
                                              const float* __restrict__ fc1w,
                                              const float* __restrict__ fc1b,
                                              const float* __restrict__ fc2w,
                                              const float* __restrict__ fc2b,
                                              float* __restrict__ out, int G) {
  __shared__ float pooled[HID];
  __shared__ float z1[HID];
  int g = blockIdx.x;
  int c = threadIdx.x;
  float cn = fmaxf((float)cnt[g], 1.f);
  pooled[c] = psum[g * HID + c] / cn;
  __syncthreads();
  float a = fc1b[c];
#pragma unroll 8
  for (int k = 0; k < HID; ++k) a += pooled[k] * fc1w[k * HID + c];
  z1[c] = fmaxf(a, 0.f);
  __syncthreads();
  if (c < 16) {
    float o = fc2b[c];
#pragma unroll 8
    for (int k = 0; k < HID; ++k) o += z1[k] * fc2w[k * 16 + c];
    out[g * 16 + c] = o;
  }
}

extern "C" void kernel_launch(void* const* d_in, const int* in_sizes, int n_in,
                              void* d_out, int out_size, void* d_ws, size_t ws_size,
                              hipStream_t stream) {
  const float* x     = (const float*)d_in[0];
  const int*   ei    = (const int*)d_in[1];
  const int*   batch = (const int*)d_in[2];
  const float* w1    = (const float*)d_in[3];
  const float* b1    = (const float*)d_in[4];
  const float* w2    = (const float*)d_in[5];
  const float* b2    = (const float*)d_in[6];
  const float* w3    = (const float*)d_in[7];
  const float* b3    = (const float*)d_in[8];
  const float* fc1w  = (const float*)d_in[9];
  const float* fc1b  = (const float*)d_in[10];
  const float* fc2w  = (const float*)d_in[11];
  const float* fc2b  = (const float*)d_in[12];
  float* out = (float*)d_out;

  const int IN = in_sizes[3] / HID;   // 260
  const int N  = in_sizes[0] / IN;    // 100000
  const int E  = in_sizes[1] / 2;     // 3200000
  const int G  = out_size / 16;       // 64

  const int* srcp = ei;
  const int* dstp = ei + E;

  // ---- workspace carve (all 256B-aligned) ----
  char* wsp = (char*)d_ws;
  auto alloc = [&](size_t bytes) {
    char* p = wsp;
    wsp += (bytes + 255) & ~(size_t)255;
    return p;
  };
  int*   deg      = (int*)alloc((size_t)N * 4);
  int*   cursor   = (int*)alloc((size_t)N * 4);
  int*   rowstart = (int*)alloc((size_t)N * 4);
  int*   bsum     = (int*)alloc(1024 * 4);
  int*   boff     = (int*)alloc(1024 * 4);
  int*   cntg     = (int*)alloc((size_t)G * 4);
  float* dinv     = (float*)alloc((size_t)N * 4);
  float* psum     = (float*)alloc((size_t)G * HID * 4);
  int*   csr      = (int*)alloc((size_t)E * 4);
  float* bufA     = (float*)alloc((size_t)N * HID * 4);
  float* bufB     = (float*)alloc((size_t)N * HID * 4);

  // ---- zero state (every call; buffers persist across graph replays) ----
  k_zero32<<<256, 256, 0, stream>>>(deg, N);
  k_zero32<<<256, 256, 0, stream>>>(cursor, N);
  k_zero32<<<4, 256, 0, stream>>>((int*)psum, G * HID);
  k_zero32<<<1, 64, 0, stream>>>(cntg, G);

  // ---- degrees + norm ----
  k_count_deg<<<1024, 256, 0, stream>>>(dstp, E, deg);
  k_dinv<<<(N + 255) / 256, 256, 0, stream>>>(deg, dinv, N);

  // ---- CSR build ----
  int nb = (N + SCAN_CHUNK - 1) / SCAN_CHUNK;
  k_scan_block_sums<<<nb, 256, 0, stream>>>(deg, N, bsum);
  k_scan_offsets<<<1, 1, 0, stream>>>(bsum, nb, boff);
  k_scan_write<<<nb, 256, 0, stream>>>(deg, N, boff, rowstart);
  k_fill_csr<<<1024, 256, 0, stream>>>(srcp, dstp, E, rowstart, cursor, csr);

  // ---- 3 GCN layers ----
  int gblocks = (N + 31) / 32;
  k_gemm<<<gblocks, 256, 0, stream>>>(x, w1, bufA, N, IN);
  k_agg<<<N, 128, 0, stream>>>(bufA, dinv, rowstart, deg, csr, b1, bufB, N);

  k_gemm<<<gblocks, 256, 0, stream>>>(bufB, w2, bufA, N, HID);
  k_agg<<<N, 128, 0, stream>>>(bufA, dinv, rowstart, deg, csr, b2, bufB, N);

  k_gemm<<<gblocks, 256, 0, stream>>>(bufB, w3, bufA, N, HID);
  k_agg<<<N, 128, 0, stream>>>(bufA, dinv, rowstart, deg, csr, b3, bufB, N);

  // ---- pool + head ----
  k_cnt<<<256, 256, 0, stream>>>(batch, N, cntg);
  int pblocks = (N + POOL_CHUNK - 1) / POOL_CHUNK;
  k_pool<<<pblocks, 128, 0, stream>>>(bufB, batch, psum, N);
  k_head<<<G, 128, 0, stream>>>(psum, cntg, fc1w, fc1b, fc2w, fc2b, out, G);
}

// Round 2
// 1420.936 us; speedup vs baseline: 1.3906x; 1.3906x over previous
//
#include <hip/hip_runtime.h>

#define HID 128
#define SCAN_CHUNK 1024
#define POOL_CHUNK 512

// ---------------- utility: fill int buffers ----------------
__global__ void k_fill32(int* __restrict__ p, int n, int val) {
  int i = blockIdx.x * blockDim.x + threadIdx.x;
  int stride = gridDim.x * blockDim.x;
  for (; i < n; i += stride) p[i] = val;
}

// ---------------- degree count (int atomics, deterministic) ----------------
__global__ void k_count_deg(const int* __restrict__ dst, int E, int* __restrict__ deg) {
  int i = blockIdx.x * blockDim.x + threadIdx.x;
  int stride = gridDim.x * blockDim.x;
  for (; i < E; i += stride) atomicAdd(&deg[dst[i]], 1);
}

__global__ void k_dinv(const int* __restrict__ deg, float* __restrict__ dinv, int N) {
  int i = blockIdx.x * blockDim.x + threadIdx.x;
  int stride = gridDim.x * blockDim.x;
  for (; i < N; i += stride) dinv[i] = rsqrtf((float)(deg[i] + 1)); // +1 = self loop
}

// ---------------- exclusive scan of deg -> rowstart (3 kernels) ----------------
__global__ void k_scan_block_sums(const int* __restrict__ deg, int N, int* __restrict__ bsum) {
  __shared__ int sh[256];
  int base = blockIdx.x * SCAN_CHUNK;
  int t = threadIdx.x;
  int s = 0;
#pragma unroll
  for (int j = 0; j < 4; ++j) {
    int idx = base + t * 4 + j;
    if (idx < N) s += deg[idx];
  }
  sh[t] = s;
  __syncthreads();
  for (int off = 128; off > 0; off >>= 1) {
    if (t < off) sh[t] += sh[t + off];
    __syncthreads();
  }
  if (t == 0) bsum[blockIdx.x] = sh[0];
}

__global__ void k_scan_offsets(const int* __restrict__ bsum, int nb, int* __restrict__ boff) {
  if (blockIdx.x == 0 && threadIdx.x == 0) {
    int run = 0;
    for (int i = 0; i < nb; ++i) { boff[i] = run; run += bsum[i]; }
  }
}

__global__ void k_scan_write(const int* __restrict__ deg, int N,
                             const int* __restrict__ boff, int* __restrict__ rowstart) {
  __shared__ int sh[256];
  int base = blockIdx.x * SCAN_CHUNK;
  int t = threadIdx.x;
  int v[4];
  int s = 0;
#pragma unroll
  for (int j = 0; j < 4; ++j) {
    int idx = base + t * 4 + j;
    v[j] = (idx < N) ? deg[idx] : 0;
    s += v[j];
  }
  sh[t] = s;
  __syncthreads();
  // Hillis-Steele inclusive scan over 256 thread sums
  for (int off = 1; off < 256; off <<= 1) {
    int x = 0;
    if (t >= off) x = sh[t - off];
    __syncthreads();
    sh[t] += x;
    __syncthreads();
  }
  int excl = sh[t] - s;
  int run = boff[blockIdx.x] + excl;
#pragma unroll
  for (int j = 0; j < 4; ++j) {
    int idx = base + t * 4 + j;
    if (idx < N) rowstart[idx] = run;
    run += v[j];
  }
}

__global__ void k_fill_csr(const int* __restrict__ src, const int* __restrict__ dst, int E,
                           const int* __restrict__ rowstart, int* __restrict__ cursor,
                           int* __restrict__ csr) {
  int i = blockIdx.x * blockDim.x + threadIdx.x;
  int stride = gridDim.x * blockDim.x;
  for (; i < E; i += stride) {
    int d = dst[i];
    int pos = rowstart[d] + atomicAdd(&cursor[d], 1);
    csr[pos] = src[i];
  }
}

// ---------------- dense GEMM: C[N][128] = A[N][K] @ W[K][128] ----------------
// block = 256 threads, tile = 64 rows x 128 cols, K-tile = 32
__global__ __launch_bounds__(256) void k_gemm(const float* __restrict__ A,
                                              const float* __restrict__ W,
                                              float* __restrict__ C, int N, int K) {
  __shared__ float As[64][33];
  __shared__ float Ws[32][128];
  int t = threadIdx.x;
  int tx = t & 31;   // column quad (c = tx*4)
  int ty = t >> 5;   // 0..7 row group
  int r0 = blockIdx.x * 64;
  float4 acc[8];
#pragma unroll
  for (int r = 0; r < 8; ++r) acc[r] = make_float4(0.f, 0.f, 0.f, 0.f);

  int lr = t >> 2;        // 0..63: A-tile load row
  int lk0 = (t & 3) * 8;  // 0,8,16,24: A-tile load k-octet

  for (int kt = 0; kt < K; kt += 32) {
    // A tile 64x32 (zero-padded): each thread loads 2 float4s
    {
      int gr = r0 + lr;
#pragma unroll
      for (int h = 0; h < 2; ++h) {
        int lk = lk0 + h * 4;
        float4 av = make_float4(0.f, 0.f, 0.f, 0.f);
        if (gr < N) {
          int kb = kt + lk;
          if (kb + 3 < K) {
            av = *(const float4*)&A[(long)gr * K + kb];
          } else {
            float tmp[4] = {0.f, 0.f, 0.f, 0.f};
            for (int j = 0; j < 4; ++j)
              if (kb + j < K) tmp[j] = A[(long)gr * K + kb + j];
            av = make_float4(tmp[0], tmp[1], tmp[2], tmp[3]);
          }
        }
        As[lr][lk + 0] = av.x; As[lr][lk + 1] = av.y;
        As[lr][lk + 2] = av.z; As[lr][lk + 3] = av.w;
      }
    }
    // W tile 32x128 (zero-padded rows past K)
#pragma unroll
    for (int i = 0; i < 4; ++i) {
      int wr = i * 8 + ty;
      int gk = kt + wr;
      float4 wv = make_float4(0.f, 0.f, 0.f, 0.f);
      if (gk < K) wv = *(const float4*)&W[(long)gk * HID + tx * 4];
      *(float4*)&Ws[wr][tx * 4] = wv;
    }
    __syncthreads();
#pragma unroll
    for (int kk = 0; kk < 32; ++kk) {
      float4 wv = *(float4*)&Ws[kk][tx * 4];
#pragma unroll
      for (int r = 0; r < 8; ++r) {
        float a = As[r * 8 + ty][kk];
        acc[r].x += a * wv.x; acc[r].y += a * wv.y;
        acc[r].z += a * wv.z; acc[r].w += a * wv.w;
      }
    }
    __syncthreads();
  }
#pragma unroll
  for (int r = 0; r < 8; ++r) {
    int gr = r0 + r * 8 + ty;
    if (gr < N) *(float4*)&C[(long)gr * HID + tx * 4] = acc[r];
  }
}

// ---------------- pull aggregation + bias + relu ----------------
// out[i][c] = relu( dinv[i]*( dinv[i]*T[i][c] + sum_nbr dinv[s]*T[s][c] ) + b[c] )
__global__ __launch_bounds__(128) void k_agg(const float* __restrict__ T,
                                             const float* __restrict__ dinv,
                                             const int* __restrict__ rowstart,
                                             const int* __restrict__ deg,
                                             const int* __restrict__ csr,
                                             const float* __restrict__ bias,
                                             float* __restrict__ out, int N) {
  int i = blockIdx.x;
  if (i >= N) return;
  int c = threadIdx.x;
  float di = dinv[i];
  float acc = di * T[(long)i * HID + c];  // self loop (x di again below)
  int s0 = rowstart[i];
  int d = deg[i];
  int j = 0;
  for (; j + 1 < d; j += 2) {
    int s1 = csr[s0 + j];
    int s2 = csr[s0 + j + 1];
    float d1 = dinv[s1];
    float d2 = dinv[s2];
    acc += d1 * T[(long)s1 * HID + c] + d2 * T[(long)s2 * HID + c];
  }
  if (j < d) {
    int s = csr[s0 + j];
    acc += dinv[s] * T[(long)s * HID + c];
  }
  float v = di * acc + bias[c];
  out[(long)i * HID + c] = fmaxf(v, 0.f);
}

// ---------------- graph start offsets from sorted batch (no atomics) ----------------
__global__ void k_starts(const int* __restrict__ batch, int N, int* __restrict__ start) {
  int i = blockIdx.x * blockDim.x + threadIdx.x;
  int stride = gridDim.x * blockDim.x;
  for (; i < N; i += stride) {
    int g = batch[i];
    if (i == 0) {
      start[g] = 0;
    } else if (batch[i - 1] != g) {
      start[g] = i;
    }
  }
}

// back-fill empty graphs: start[g]==-1 -> start[g+1]
__global__ void k_fix_starts(int* __restrict__ start, int G, int N) {
  if (blockIdx.x == 0 && threadIdx.x == 0) {
    start[G] = N;
    for (int g = G - 1; g >= 0; --g)
      if (start[g] < 0) start[g] = start[g + 1];
  }
}

// ---------------- mean-pool partial sums (batch is sorted) ----------------
__global__ __launch_bounds__(128) void k_pool(const float* __restrict__ h,
                                              const int* __restrict__ batch,
                                              float* __restrict__ psum, int N) {
  __shared__ int bsh[POOL_CHUNK];
  int c = threadIdx.x;
  int start = blockIdx.x * POOL_CHUNK;
  int end = min(N, start + POOL_CHUNK);
  int len = end - start;
  if (len <= 0) return;
  for (int i = c; i < len; i += 128) bsh[i] = batch[start + i];
  __syncthreads();
  int cur = bsh[0];
  float acc = 0.f;
  for (int i = 0; i < len; ++i) {
    int g = bsh[i];
    if (g != cur) {
      atomicAdd(&psum[cur * HID + c], acc);
      acc = 0.f;
      cur = g;
    }
    acc += h[(long)(start + i) * HID + c];
  }
  atomicAdd(&psum[cur * HID + c], acc);
}

// ---------------- MLP head: one block per graph ----------------
__global__ __launch_bounds__(128) void k_head(const float* __restrict__ psum,
                                              const int* __restrict__ gstart,
                                              const float* __restrict__ fc1w,
                                              const float* __restrict__ fc1b,
                                              const float* __restrict__ fc2w,
                                              const float* __restrict__ fc2b,
                                              float* __restrict__ out, int G) {
  __shared__ float pooled[HID];
  __shared__ float z1[HID];
  int g = blockIdx.x;
  int c = threadIdx.x;
  float cn = fmaxf((float)(gstart[g + 1] - gstart[g]), 1.f);
  pooled[c] = psum[g * HID + c] / cn;
  __syncthreads();
  float a = fc1b[c];
#pragma unroll 8
  for (int k = 0; k < HID; ++k) a += pooled[k] * fc1w[k * HID + c];
  z1[c] = fmaxf(a, 0.f);
  __syncthreads();
  if (c < 16) {
    float o = fc2b[c];
#pragma unroll 8
    for (int k = 0; k < HID; ++k) o += z1[k] * fc2w[k * 16 + c];
    out[g * 16 + c] = o;
  }
}

extern "C" void kernel_launch(void* const* d_in, const int* in_sizes, int n_in,
                              void* d_out, int out_size, void* d_ws, size_t ws_size,
                              hipStream_t stream) {
  const float* x     = (const float*)d_in[0];
  const int*   ei    = (const int*)d_in[1];
  const int*   batch = (const int*)d_in[2];
  const float* w1    = (const float*)d_in[3];
  const float* b1    = (const float*)d_in[4];
  const float* w2    = (const float*)d_in[5];
  const float* b2    = (const float*)d_in[6];
  const float* w3    = (const float*)d_in[7];
  const float* b3    = (const float*)d_in[8];
  const float* fc1w  = (const float*)d_in[9];
  const float* fc1b  = (const float*)d_in[10];
  const float* fc2w  = (const float*)d_in[11];
  const float* fc2b  = (const float*)d_in[12];
  float* out = (float*)d_out;

  const int IN = in_sizes[3] / HID;   // 260
  const int N  = in_sizes[0] / IN;    // 100000
  const int E  = in_sizes[1] / 2;     // 3200000
  const int G  = out_size / 16;       // 64

  const int* srcp = ei;
  const int* dstp = ei + E;

  // ---- workspace carve (all 256B-aligned) ----
  char* wsp = (char*)d_ws;
  auto alloc = [&](size_t bytes) {
    char* p = wsp;
    wsp += (bytes + 255) & ~(size_t)255;
    return p;
  };
  int*   deg      = (int*)alloc((size_t)N * 4);
  int*   cursor   = (int*)alloc((size_t)N * 4);
  int*   rowstart = (int*)alloc((size_t)N * 4);
  int*   bsum     = (int*)alloc(1024 * 4);
  int*   boff     = (int*)alloc(1024 * 4);
  int*   gstart   = (int*)alloc((size_t)(G + 1) * 4);
  float* dinv     = (float*)alloc((size_t)N * 4);
  float* psum     = (float*)alloc((size_t)G * HID * 4);
  int*   csr      = (int*)alloc((size_t)E * 4);
  float* bufA     = (float*)alloc((size_t)N * HID * 4);
  float* bufB     = (float*)alloc((size_t)N * HID * 4);

  // ---- zero/init state (every call; buffers persist across graph replays) ----
  k_fill32<<<256, 256, 0, stream>>>(deg, N, 0);
  k_fill32<<<256, 256, 0, stream>>>(cursor, N, 0);
  k_fill32<<<4, 256, 0, stream>>>((int*)psum, G * HID, 0);
  k_fill32<<<1, 128, 0, stream>>>(gstart, G + 1, -1);

  // ---- degrees + norm ----
  k_count_deg<<<1024, 256, 0, stream>>>(dstp, E, deg);
  k_dinv<<<(N + 255) / 256, 256, 0, stream>>>(deg, dinv, N);

  // ---- CSR build ----
  int nb = (N + SCAN_CHUNK - 1) / SCAN_CHUNK;
  k_scan_block_sums<<<nb, 256, 0, stream>>>(deg, N, bsum);
  k_scan_offsets<<<1, 1, 0, stream>>>(bsum, nb, boff);
  k_scan_write<<<nb, 256, 0, stream>>>(deg, N, boff, rowstart);
  k_fill_csr<<<1024, 256, 0, stream>>>(srcp, dstp, E, rowstart, cursor, csr);

  // ---- graph boundaries (replaces atomic k_cnt) ----
  k_starts<<<256, 256, 0, stream>>>(batch, N, gstart);
  k_fix_starts<<<1, 1, 0, stream>>>(gstart, G, N);

  // ---- 3 GCN layers ----
  int gblocks = (N + 63) / 64;
  k_gemm<<<gblocks, 256, 0, stream>>>(x, w1, bufA, N, IN);
  k_agg<<<N, 128, 0, stream>>>(bufA, dinv, rowstart, deg, csr, b1, bufB, N);

  k_gemm<<<gblocks, 256, 0, stream>>>(bufB, w2, bufA, N, HID);
  k_agg<<<N, 128, 0, stream>>>(bufA, dinv, rowstart, deg, csr, b2, bufB, N);

  k_gemm<<<gblocks, 256, 0, stream>>>(bufB, w3, bufA, N, HID);
  k_agg<<<N, 128, 0, stream>>>(bufA, dinv, rowstart, deg, csr, b3, bufB, N);

  // ---- pool + head ----
  int pblocks = (N + POOL_CHUNK - 1) / POOL_CHUNK;
  k_pool<<<pblocks, 128, 0, stream>>>(bufB, batch, psum, N);
  k_head<<<G, 128, 0, stream>>>(psum, gstart, fc1w, fc1b, fc2w, fc2b, out, G);
}

// Round 3
// 1366.616 us; speedup vs baseline: 1.4459x; 1.0397x over previous
//
#include <hip/hip_runtime.h>

#define HID 128
#define SCAN_CHUNK 1024
#define POOL_CHUNK 512

// ---------------- utility: fill int buffers ----------------
__global__ void k_fill32(int* __restrict__ p, int n, int val) {
  int i = blockIdx.x * blockDim.x + threadIdx.x;
  int stride = gridDim.x * blockDim.x;
  for (; i < n; i += stride) p[i] = val;
}

// ---------------- degree count (int atomics, deterministic) ----------------
__global__ void k_count_deg(const int* __restrict__ dst, int E, int* __restrict__ deg) {
  int i = blockIdx.x * blockDim.x + threadIdx.x;
  int stride = gridDim.x * blockDim.x;
  for (; i < E; i += stride) atomicAdd(&deg[dst[i]], 1);
}

__global__ void k_dinv(const int* __restrict__ deg, float* __restrict__ dinv, int N) {
  int i = blockIdx.x * blockDim.x + threadIdx.x;
  int stride = gridDim.x * blockDim.x;
  for (; i < N; i += stride) dinv[i] = rsqrtf((float)(deg[i] + 1)); // +1 = self loop
}

// ---------------- exclusive scan of deg -> rowstart (3 kernels) ----------------
__global__ void k_scan_block_sums(const int* __restrict__ deg, int N, int* __restrict__ bsum) {
  __shared__ int sh[256];
  int base = blockIdx.x * SCAN_CHUNK;
  int t = threadIdx.x;
  int s = 0;
#pragma unroll
  for (int j = 0; j < 4; ++j) {
    int idx = base + t * 4 + j;
    if (idx < N) s += deg[idx];
  }
  sh[t] = s;
  __syncthreads();
  for (int off = 128; off > 0; off >>= 1) {
    if (t < off) sh[t] += sh[t + off];
    __syncthreads();
  }
  if (t == 0) bsum[blockIdx.x] = sh[0];
}

__global__ void k_scan_offsets(const int* __restrict__ bsum, int nb, int* __restrict__ boff) {
  if (blockIdx.x == 0 && threadIdx.x == 0) {
    int run = 0;
    for (int i = 0; i < nb; ++i) { boff[i] = run; run += bsum[i]; }
  }
}

__global__ void k_scan_write(const int* __restrict__ deg, int N,
                             const int* __restrict__ boff, int* __restrict__ rowstart) {
  __shared__ int sh[256];
  int base = blockIdx.x * SCAN_CHUNK;
  int t = threadIdx.x;
  int v[4];
  int s = 0;
#pragma unroll
  for (int j = 0; j < 4; ++j) {
    int idx = base + t * 4 + j;
    v[j] = (idx < N) ? deg[idx] : 0;
    s += v[j];
  }
  sh[t] = s;
  __syncthreads();
  for (int off = 1; off < 256; off <<= 1) {
    int x = 0;
    if (t >= off) x = sh[t - off];
    __syncthreads();
    sh[t] += x;
    __syncthreads();
  }
  int excl = sh[t] - s;
  int run = boff[blockIdx.x] + excl;
#pragma unroll
  for (int j = 0; j < 4; ++j) {
    int idx = base + t * 4 + j;
    if (idx < N) rowstart[idx] = run;
    run += v[j];
  }
}

__global__ void k_fill_csr(const int* __restrict__ src, const int* __restrict__ dst, int E,
                           const int* __restrict__ rowstart, int* __restrict__ cursor,
                           int* __restrict__ csr) {
  int i = blockIdx.x * blockDim.x + threadIdx.x;
  int stride = gridDim.x * blockDim.x;
  for (; i < E; i += stride) {
    int d = dst[i];
    int pos = rowstart[d] + atomicAdd(&cursor[d], 1);
    csr[pos] = src[i];
  }
}

// ---------------- dense GEMM: C[N][128] = dscale(row) * (A[N][K] @ W[K][128]) ----
// block = 256 threads, tile = 128 rows x 128 cols, K-tile = 16, 8x8 per thread
__global__ __launch_bounds__(256) void k_gemm(const float* __restrict__ A,
                                              const float* __restrict__ W,
                                              const float* __restrict__ dscale,
                                              float* __restrict__ C, int N, int K) {
  __shared__ float As[16][132];   // transposed A tile: As[k][row]
  __shared__ float Ws[16][128];   // Ws[k][col]
  int t = threadIdx.x;
  int tx = t & 15;    // col group: cols tx*8 .. tx*8+7
  int ty = t >> 4;    // row group: rows ty*8 .. ty*8+7
  int r0 = blockIdx.x * 128;

  float4 acc0[8], acc1[8];
#pragma unroll
  for (int r = 0; r < 8; ++r) {
    acc0[r] = make_float4(0.f, 0.f, 0.f, 0.f);
    acc1[r] = make_float4(0.f, 0.f, 0.f, 0.f);
  }

  for (int kt = 0; kt < K; kt += 16) {
    // ---- stage A tile 128x16 (transposed into As[k][row]) ----
#pragma unroll
    for (int p = 0; p < 2; ++p) {
      int idx = t + p * 256;
      int row = idx >> 2;           // 0..127
      int kq = (idx & 3) * 4;       // 0,4,8,12
      int gr = r0 + row;
      int kb = kt + kq;
      float4 av = make_float4(0.f, 0.f, 0.f, 0.f);
      if (gr < N && kb < K)         // K % 4 == 0, quad fully valid when kb < K
        av = *(const float4*)&A[(long)gr * K + kb];
      As[kq + 0][row] = av.x;
      As[kq + 1][row] = av.y;
      As[kq + 2][row] = av.z;
      As[kq + 3][row] = av.w;
    }
    // ---- stage W tile 16x128 ----
#pragma unroll
    for (int p = 0; p < 2; ++p) {
      int idx = t + p * 256;
      int wr = idx >> 5;            // 0..15
      int wc = (idx & 31) * 4;      // 0..124
      int gk = kt + wr;
      float4 wv = make_float4(0.f, 0.f, 0.f, 0.f);
      if (gk < K) wv = *(const float4*)&W[(long)gk * HID + wc];
      *(float4*)&Ws[wr][wc] = wv;
    }
    __syncthreads();
#pragma unroll
    for (int kk = 0; kk < 16; ++kk) {
      float4 a0 = *(float4*)&As[kk][ty * 8];
      float4 a1 = *(float4*)&As[kk][ty * 8 + 4];
      float4 w0 = *(float4*)&Ws[kk][tx * 8];
      float4 w1 = *(float4*)&Ws[kk][tx * 8 + 4];
      float ar[8] = {a0.x, a0.y, a0.z, a0.w, a1.x, a1.y, a1.z, a1.w};
#pragma unroll
      for (int r = 0; r < 8; ++r) {
        float a = ar[r];
        acc0[r].x += a * w0.x; acc0[r].y += a * w0.y;
        acc0[r].z += a * w0.z; acc0[r].w += a * w0.w;
        acc1[r].x += a * w1.x; acc1[r].y += a * w1.y;
        acc1[r].z += a * w1.z; acc1[r].w += a * w1.w;
      }
    }
    __syncthreads();
  }
#pragma unroll
  for (int r = 0; r < 8; ++r) {
    int gr = r0 + ty * 8 + r;
    if (gr < N) {
      float s = dscale ? dscale[gr] : 1.0f;
      float4 v0 = make_float4(acc0[r].x * s, acc0[r].y * s, acc0[r].z * s, acc0[r].w * s);
      float4 v1 = make_float4(acc1[r].x * s, acc1[r].y * s, acc1[r].z * s, acc1[r].w * s);
      *(float4*)&C[(long)gr * HID + tx * 8] = v0;
      *(float4*)&C[(long)gr * HID + tx * 8 + 4] = v1;
    }
  }
}

// ---------------- pull aggregation + bias + relu ----------------
// T is pre-scaled by dinv (done in GEMM epilogue):
// out[i][c] = relu( dinv[i] * ( T[i][c] + sum_nbr T[s][c] ) + b[c] )
// block = 256 threads: 8 neighbor-groups x 32 lanes (each lane = 4 channels)
__global__ __launch_bounds__(256) void k_agg(const float* __restrict__ T,
                                             const float* __restrict__ dinv,
                                             const int* __restrict__ rowstart,
                                             const int* __restrict__ deg,
                                             const int* __restrict__ csr,
                                             const float* __restrict__ bias,
                                             float* __restrict__ out, int N) {
  __shared__ float sh[8][128];
  int i = blockIdx.x;
  int t = threadIdx.x;
  int g = t >> 5;          // neighbor group 0..7
  int lc = (t & 31) * 4;   // channel quad

  const float4* T4 = (const float4*)T;
  long selfbase = (long)i * 32 + (lc >> 2);

  float4 acc;
  if (g == 0) acc = T4[selfbase];                 // self-loop term (pre-scaled)
  else        acc = make_float4(0.f, 0.f, 0.f, 0.f);

  int s0 = rowstart[i];
  int d = deg[i];
  int j = g;
  for (; j + 8 < d; j += 16) {
    int s1 = csr[s0 + j];
    int s2 = csr[s0 + j + 8];
    float4 v1 = T4[(long)s1 * 32 + (lc >> 2)];
    float4 v2 = T4[(long)s2 * 32 + (lc >> 2)];
    acc.x += v1.x + v2.x; acc.y += v1.y + v2.y;
    acc.z += v1.z + v2.z; acc.w += v1.w + v2.w;
  }
  if (j < d) {
    int s1 = csr[s0 + j];
    float4 v1 = T4[(long)s1 * 32 + (lc >> 2)];
    acc.x += v1.x; acc.y += v1.y; acc.z += v1.z; acc.w += v1.w;
  }
  *(float4*)&sh[g][lc] = acc;
  __syncthreads();
  if (t < 128) {
    float total = 0.f;
#pragma unroll
    for (int gg = 0; gg < 8; ++gg) total += sh[gg][t];
    float di = dinv[i];
    out[(long)i * HID + t] = fmaxf(di * total + bias[t], 0.f);
  }
}

// ---------------- graph start offsets from sorted batch (no atomics) ----------------
__global__ void k_starts(const int* __restrict__ batch, int N, int* __restrict__ start) {
  int i = blockIdx.x * blockDim.x + threadIdx.x;
  int stride = gridDim.x * blockDim.x;
  for (; i < N; i += stride) {
    int g = batch[i];
    if (i == 0) {
      start[g] = 0;
    } else if (batch[i - 1] != g) {
      start[g] = i;
    }
  }
}

// back-fill empty graphs: start[g]==-1 -> start[g+1]
__global__ void k_fix_starts(int* __restrict__ start, int G, int N) {
  if (blockIdx.x == 0 && threadIdx.x == 0) {
    start[G] = N;
    for (int g = G - 1; g >= 0; --g)
      if (start[g] < 0) start[g] = start[g + 1];
  }
}

// ---------------- mean-pool partial sums (batch is sorted) ----------------
__global__ __launch_bounds__(128) void k_pool(const float* __restrict__ h,
                                              const int* __restrict__ batch,
                                              float* __restrict__ psum, int N) {
  __shared__ int bsh[POOL_CHUNK];
  int c = threadIdx.x;
  int start = blockIdx.x * POOL_CHUNK;
  int end = min(N, start + POOL_CHUNK);
  int len = end - start;
  if (len <= 0) return;
  for (int i = c; i < len; i += 128) bsh[i] = batch[start + i];
  __syncthreads();
  int cur = bsh[0];
  float acc = 0.f;
  for (int i = 0; i < len; ++i) {
    int g = bsh[i];
    if (g != cur) {
      atomicAdd(&psum[cur * HID + c], acc);
      acc = 0.f;
      cur = g;
    }
    acc += h[(long)(start + i) * HID + c];
  }
  atomicAdd(&psum[cur * HID + c], acc);
}

// ---------------- MLP head: one block per graph ----------------
__global__ __launch_bounds__(128) void k_head(const float* __restrict__ psum,
                                              const int* __restrict__ gstart,
                                              const float* __restrict__ fc1w,
                                              const float* __restrict__ fc1b,
                                              const float* __restrict__ fc2w,
                                              const float* __restrict__ fc2b,
                                              float* __restrict__ out, int G) {
  __shared__ float pooled[HID];
  __shared__ float z1[HID];
  int g = blockIdx.x;
  int c = threadIdx.x;
  float cn = fmaxf((float)(gstart[g + 1] - gstart[g]), 1.f);
  pooled[c] = psum[g * HID + c] / cn;
  __syncthreads();
  float a = fc1b[c];
#pragma unroll 8
  for (int k = 0; k < HID; ++k) a += pooled[k] * fc1w[k * HID + c];
  z1[c] = fmaxf(a, 0.f);
  __syncthreads();
  if (c < 16) {
    float o = fc2b[c];
#pragma unroll 8
    for (int k = 0; k < HID; ++k) o += z1[k] * fc2w[k * 16 + c];
    out[g * 16 + c] = o;
  }
}

extern "C" void kernel_launch(void* const* d_in, const int* in_sizes, int n_in,
                              void* d_out, int out_size, void* d_ws, size_t ws_size,
                              hipStream_t stream) {
  const float* x     = (const float*)d_in[0];
  const int*   ei    = (const int*)d_in[1];
  const int*   batch = (const int*)d_in[2];
  const float* w1    = (const float*)d_in[3];
  const float* b1    = (const float*)d_in[4];
  const float* w2    = (const float*)d_in[5];
  const float* b2    = (const float*)d_in[6];
  const float* w3    = (const float*)d_in[7];
  const float* b3    = (const float*)d_in[8];
  const float* fc1w  = (const float*)d_in[9];
  const float* fc1b  = (const float*)d_in[10];
  const float* fc2w  = (const float*)d_in[11];
  const float* fc2b  = (const float*)d_in[12];
  float* out = (float*)d_out;

  const int IN = in_sizes[3] / HID;   // 260
  const int N  = in_sizes[0] / IN;    // 100000
  const int E  = in_sizes[1] / 2;     // 3200000
  const int G  = out_size / 16;       // 64

  const int* srcp = ei;
  const int* dstp = ei + E;

  // ---- workspace carve (all 256B-aligned) ----
  char* wsp = (char*)d_ws;
  auto alloc = [&](size_t bytes) {
    char* p = wsp;
    wsp += (bytes + 255) & ~(size_t)255;
    return p;
  };
  int*   deg      = (int*)alloc((size_t)N * 4);
  int*   cursor   = (int*)alloc((size_t)N * 4);
  int*   rowstart = (int*)alloc((size_t)N * 4);
  int*   bsum     = (int*)alloc(1024 * 4);
  int*   boff     = (int*)alloc(1024 * 4);
  int*   gstart   = (int*)alloc((size_t)(G + 1) * 4);
  float* dinv     = (float*)alloc((size_t)N * 4);
  float* psum     = (float*)alloc((size_t)G * HID * 4);
  int*   csr      = (int*)alloc((size_t)E * 4);
  float* bufA     = (float*)alloc((size_t)N * HID * 4);
  float* bufB     = (float*)alloc((size_t)N * HID * 4);

  // ---- zero/init state (every call; buffers persist across graph replays) ----
  k_fill32<<<256, 256, 0, stream>>>(deg, N, 0);
  k_fill32<<<256, 256, 0, stream>>>(cursor, N, 0);
  k_fill32<<<4, 256, 0, stream>>>((int*)psum, G * HID, 0);
  k_fill32<<<1, 128, 0, stream>>>(gstart, G + 1, -1);

  // ---- degrees + norm ----
  k_count_deg<<<1024, 256, 0, stream>>>(dstp, E, deg);
  k_dinv<<<(N + 255) / 256, 256, 0, stream>>>(deg, dinv, N);

  // ---- CSR build ----
  int nb = (N + SCAN_CHUNK - 1) / SCAN_CHUNK;
  k_scan_block_sums<<<nb, 256, 0, stream>>>(deg, N, bsum);
  k_scan_offsets<<<1, 1, 0, stream>>>(bsum, nb, boff);
  k_scan_write<<<nb, 256, 0, stream>>>(deg, N, boff, rowstart);
  k_fill_csr<<<1024, 256, 0, stream>>>(srcp, dstp, E, rowstart, cursor, csr);

  // ---- graph boundaries ----
  k_starts<<<256, 256, 0, stream>>>(batch, N, gstart);
  k_fix_starts<<<1, 1, 0, stream>>>(gstart, G, N);

  // ---- 3 GCN layers (GEMM epilogue pre-scales rows by dinv) ----
  int gblocks = (N + 127) / 128;
  k_gemm<<<gblocks, 256, 0, stream>>>(x, w1, dinv, bufA, N, IN);
  k_agg<<<N, 256, 0, stream>>>(bufA, dinv, rowstart, deg, csr, b1, bufB, N);

  k_gemm<<<gblocks, 256, 0, stream>>>(bufB, w2, dinv, bufA, N, HID);
  k_agg<<<N, 256, 0, stream>>>(bufA, dinv, rowstart, deg, csr, b2, bufB, N);

  k_gemm<<<gblocks, 256, 0, stream>>>(bufB, w3, dinv, bufA, N, HID);
  k_agg<<<N, 256, 0, stream>>>(bufA, dinv, rowstart, deg, csr, b3, bufB, N);

  // ---- pool + head ----
  int pblocks = (N + POOL_CHUNK - 1) / POOL_CHUNK;
  k_pool<<<pblocks, 128, 0, stream>>>(bufB, batch, psum, N);
  k_head<<<G, 128, 0, stream>>>(psum, gstart, fc1w, fc1b, fc2w, fc2b, out, G);
}

// Round 4
// 1179.304 us; speedup vs baseline: 1.6755x; 1.1588x over previous
//
#include <hip/hip_runtime.h>

#define HID 128
#define SCAN_CHUNK 1024
#define POOL_CHUNK 512

// binned CSR build params
#define NB 256      // buckets over dst space (monotone: b = dst*NB/N)
#define BW 400      // max bucket width (ceil(100000/256)=391)
#define DEPTH 24    // LDS staging depth per bucket per round
#define CH 2048     // edges per block per round

// ---------------- utility: fill int buffers ----------------
__global__ void k_fill32(int* __restrict__ p, int n, int val) {
  int i = blockIdx.x * blockDim.x + threadIdx.x;
  int stride = gridDim.x * blockDim.x;
  for (; i < n; i += stride) p[i] = val;
}

// ---------------- bucket histogram (LDS-staged) ----------------
__global__ __launch_bounds__(256) void k_hist(const int* __restrict__ dst, int E, int N,
                                              int* __restrict__ bhist) {
  __shared__ int h[NB];
  int t = threadIdx.x;
  h[t] = 0;
  __syncthreads();
  int i = blockIdx.x * blockDim.x + t;
  int stride = gridDim.x * blockDim.x;
  for (; i < E; i += stride) {
    int b = (int)(((long long)dst[i] * NB) / N);
    atomicAdd(&h[b], 1);
  }
  __syncthreads();
  if (h[t]) atomicAdd(&bhist[t], h[t]);
}

__global__ void k_bscan(const int* __restrict__ bhist, int* __restrict__ bstart,
                        int* __restrict__ gcur, int E) {
  if (blockIdx.x == 0 && threadIdx.x == 0) {
    int run = 0;
    for (int b = 0; b < NB; ++b) { bstart[b] = run; gcur[b] = run; run += bhist[b]; }
    bstart[NB] = run; // == E
  }
}

// ---------------- LDS-staged scatter into bucket-major order ----------------
__global__ __launch_bounds__(256) void k_scatter(const int* __restrict__ src,
                                                 const int* __restrict__ dst,
                                                 int E, int N,
                                                 unsigned long long* __restrict__ binned,
                                                 int* __restrict__ gcur) {
  __shared__ unsigned long long buf[NB][DEPTH]; // 48 KB
  __shared__ int cnt[NB];
  int t = threadIdx.x;
  long cover = (long)gridDim.x * CH;
  int nround = (int)((E + cover - 1) / cover);
  for (int r = 0; r < nround; ++r) {
    cnt[t] = 0;
    __syncthreads();
    long base = (long)r * cover + (long)blockIdx.x * CH;
#pragma unroll
    for (int k = 0; k < CH / 256; ++k) {
      long i = base + k * 256 + t;
      if (i < E) {
        int s = src[i], d = dst[i];
        int b = (int)(((long long)d * NB) / N);
        unsigned long long pack =
            ((unsigned long long)(unsigned)d << 32) | (unsigned)s;
        int slot = atomicAdd(&cnt[b], 1);
        if (slot < DEPTH) buf[b][slot] = pack;
        else { int g = atomicAdd(&gcur[b], 1); binned[g] = pack; } // rare spill
      }
    }
    __syncthreads();
    // flush: thread t owns bucket t
    {
      int c = cnt[t];
      if (c > DEPTH) c = DEPTH;
      if (c > 0) {
        int g = atomicAdd(&gcur[t], c);
        for (int k = 0; k < c; ++k) binned[g + k] = buf[t][k];
      }
    }
    __syncthreads();
  }
}

// ---------------- per-bucket degree histogram (replaces global atomic count) ----
__global__ __launch_bounds__(256) void k_bdeg(const unsigned long long* __restrict__ binned,
                                              const int* __restrict__ bstart, int N,
                                              int* __restrict__ deg) {
  __shared__ int hist[BW];
  int b = blockIdx.x;
  int t = threadIdx.x;
  int d0 = (int)(((long long)b * N + NB - 1) / NB);
  int d1 = (int)(((long long)(b + 1) * N + NB - 1) / NB);
  if (d1 > N) d1 = N;
  int W = d1 - d0;
  for (int w = t; w < W; w += 256) hist[w] = 0;
  __syncthreads();
  int s = bstart[b], e = bstart[b + 1];
  for (int i = s + t; i < e; i += 256) {
    int d = (int)(binned[i] >> 32);
    atomicAdd(&hist[d - d0], 1);
  }
  __syncthreads();
  for (int w = t; w < W; w += 256) deg[d0 + w] = hist[w];
}

__global__ void k_dinv(const int* __restrict__ deg, float* __restrict__ dinv, int N) {
  int i = blockIdx.x * blockDim.x + threadIdx.x;
  int stride = gridDim.x * blockDim.x;
  for (; i < N; i += stride) dinv[i] = rsqrtf((float)(deg[i] + 1)); // +1 = self loop
}

// ---------------- exclusive scan of deg -> rowstart (3 kernels) ----------------
__global__ void k_scan_block_sums(const int* __restrict__ deg, int N, int* __restrict__ bsum) {
  __shared__ int sh[256];
  int base = blockIdx.x * SCAN_CHUNK;
  int t = threadIdx.x;
  int s = 0;
#pragma unroll
  for (int j = 0; j < 4; ++j) {
    int idx = base + t * 4 + j;
    if (idx < N) s += deg[idx];
  }
  sh[t] = s;
  __syncthreads();
  for (int off = 128; off > 0; off >>= 1) {
    if (t < off) sh[t] += sh[t + off];
    __syncthreads();
  }
  if (t == 0) bsum[blockIdx.x] = sh[0];
}

__global__ void k_scan_offsets(const int* __restrict__ bsum, int nb, int* __restrict__ boff) {
  if (blockIdx.x == 0 && threadIdx.x == 0) {
    int run = 0;
    for (int i = 0; i < nb; ++i) { boff[i] = run; run += bsum[i]; }
  }
}

__global__ void k_scan_write(const int* __restrict__ deg, int N,
                             const int* __restrict__ boff, int* __restrict__ rowstart) {
  __shared__ int sh[256];
  int base = blockIdx.x * SCAN_CHUNK;
  int t = threadIdx.x;
  int v[4];
  int s = 0;
#pragma unroll
  for (int j = 0; j < 4; ++j) {
    int idx = base + t * 4 + j;
    v[j] = (idx < N) ? deg[idx] : 0;
    s += v[j];
  }
  sh[t] = s;
  __syncthreads();
  for (int off = 1; off < 256; off <<= 1) {
    int x = 0;
    if (t >= off) x = sh[t - off];
    __syncthreads();
    sh[t] += x;
    __syncthreads();
  }
  int excl = sh[t] - s;
  int run = boff[blockIdx.x] + excl;
#pragma unroll
  for (int j = 0; j < 4; ++j) {
    int idx = base + t * 4 + j;
    if (idx < N) rowstart[idx] = run;
    run += v[j];
  }
}

// ---------------- per-bucket CSR placement with LDS cursors ----------------
__global__ __launch_bounds__(256) void k_place(const unsigned long long* __restrict__ binned,
                                               const int* __restrict__ bstart,
                                               const int* __restrict__ rowstart, int N,
                                               int* __restrict__ csr) {
  __shared__ int cur[BW];
  int b = blockIdx.x;
  int t = threadIdx.x;
  int d0 = (int)(((long long)b * N + NB - 1) / NB);
  int d1 = (int)(((long long)(b + 1) * N + NB - 1) / NB);
  if (d1 > N) d1 = N;
  int W = d1 - d0;
  for (int w = t; w < W; w += 256) cur[w] = 0;
  __syncthreads();
  int s = bstart[b], e = bstart[b + 1];
  for (int i = s + t; i < e; i += 256) {
    unsigned long long p = binned[i];
    int d = (int)(p >> 32);
    int sn = (int)(p & 0xffffffffu);
    int pos = rowstart[d] + atomicAdd(&cur[d - d0], 1);
    csr[pos] = sn;
  }
}

// ---------------- dense GEMM: C[N][128] = dscale(row) * (A[N][K] @ W[K][128]) ----
// block = 256 threads, tile = 128 rows x 128 cols, K-tile = 16, 8x8 per thread
__global__ __launch_bounds__(256) void k_gemm(const float* __restrict__ A,
                                              const float* __restrict__ W,
                                              const float* __restrict__ dscale,
                                              float* __restrict__ C, int N, int K) {
  __shared__ float As[16][132];   // transposed A tile: As[k][row]
  __shared__ float Ws[16][128];   // Ws[k][col]
  int t = threadIdx.x;
  int tx = t & 15;    // col group: cols tx*8 .. tx*8+7
  int ty = t >> 4;    // row group: rows ty*8 .. ty*8+7
  int r0 = blockIdx.x * 128;

  float4 acc0[8], acc1[8];
#pragma unroll
  for (int r = 0; r < 8; ++r) {
    acc0[r] = make_float4(0.f, 0.f, 0.f, 0.f);
    acc1[r] = make_float4(0.f, 0.f, 0.f, 0.f);
  }

  for (int kt = 0; kt < K; kt += 16) {
    // ---- stage A tile 128x16 (transposed into As[k][row]) ----
#pragma unroll
    for (int p = 0; p < 2; ++p) {
      int idx = t + p * 256;
      int row = idx >> 2;           // 0..127
      int kq = (idx & 3) * 4;       // 0,4,8,12
      int gr = r0 + row;
      int kb = kt + kq;
      float4 av = make_float4(0.f, 0.f, 0.f, 0.f);
      if (gr < N && kb < K)         // K % 4 == 0, quad fully valid when kb < K
        av = *(const float4*)&A[(long)gr * K + kb];
      As[kq + 0][row] = av.x;
      As[kq + 1][row] = av.y;
      As[kq + 2][row] = av.z;
      As[kq + 3][row] = av.w;
    }
    // ---- stage W tile 16x128 ----
#pragma unroll
    for (int p = 0; p < 2; ++p) {
      int idx = t + p * 256;
      int wr = idx >> 5;            // 0..15
      int wc = (idx & 31) * 4;      // 0..124
      int gk = kt + wr;
      float4 wv = make_float4(0.f, 0.f, 0.f, 0.f);
      if (gk < K) wv = *(const float4*)&W[(long)gk * HID + wc];
      *(float4*)&Ws[wr][wc] = wv;
    }
    __syncthreads();
#pragma unroll
    for (int kk = 0; kk < 16; ++kk) {
      float4 a0 = *(float4*)&As[kk][ty * 8];
      float4 a1 = *(float4*)&As[kk][ty * 8 + 4];
      float4 w0 = *(float4*)&Ws[kk][tx * 8];
      float4 w1 = *(float4*)&Ws[kk][tx * 8 + 4];
      float ar[8] = {a0.x, a0.y, a0.z, a0.w, a1.x, a1.y, a1.z, a1.w};
#pragma unroll
      for (int r = 0; r < 8; ++r) {
        float a = ar[r];
        acc0[r].x += a * w0.x; acc0[r].y += a * w0.y;
        acc0[r].z += a * w0.z; acc0[r].w += a * w0.w;
        acc1[r].x += a * w1.x; acc1[r].y += a * w1.y;
        acc1[r].z += a * w1.z; acc1[r].w += a * w1.w;
      }
    }
    __syncthreads();
  }
#pragma unroll
  for (int r = 0; r < 8; ++r) {
    int gr = r0 + ty * 8 + r;
    if (gr < N) {
      float s = dscale ? dscale[gr] : 1.0f;
      float4 v0 = make_float4(acc0[r].x * s, acc0[r].y * s, acc0[r].z * s, acc0[r].w * s);
      float4 v1 = make_float4(acc1[r].x * s, acc1[r].y * s, acc1[r].z * s, acc1[r].w * s);
      *(float4*)&C[(long)gr * HID + tx * 8] = v0;
      *(float4*)&C[(long)gr * HID + tx * 8 + 4] = v1;
    }
  }
}

// ---------------- pull aggregation + bias + relu ----------------
// T is pre-scaled by dinv (done in GEMM epilogue):
// out[i][c] = relu( dinv[i] * ( T[i][c] + sum_nbr T[s][c] ) + b[c] )
__global__ __launch_bounds__(256) void k_agg(const float* __restrict__ T,
                                             const float* __restrict__ dinv,
                                             const int* __restrict__ rowstart,
                                             const int* __restrict__ deg,
                                             const int* __restrict__ csr,
                                             const float* __restrict__ bias,
                                             float* __restrict__ out, int N) {
  __shared__ float sh[8][128];
  int i = blockIdx.x;
  int t = threadIdx.x;
  int g = t >> 5;          // neighbor group 0..7
  int lc = (t & 31) * 4;   // channel quad

  const float4* T4 = (const float4*)T;
  long selfbase = (long)i * 32 + (lc >> 2);

  float4 acc;
  if (g == 0) acc = T4[selfbase];                 // self-loop term (pre-scaled)
  else        acc = make_float4(0.f, 0.f, 0.f, 0.f);

  int s0 = rowstart[i];
  int d = deg[i];
  int j = g;
  for (; j + 8 < d; j += 16) {
    int s1 = csr[s0 + j];
    int s2 = csr[s0 + j + 8];
    float4 v1 = T4[(long)s1 * 32 + (lc >> 2)];
    float4 v2 = T4[(long)s2 * 32 + (lc >> 2)];
    acc.x += v1.x + v2.x; acc.y += v1.y + v2.y;
    acc.z += v1.z + v2.z; acc.w += v1.w + v2.w;
  }
  if (j < d) {
    int s1 = csr[s0 + j];
    float4 v1 = T4[(long)s1 * 32 + (lc >> 2)];
    acc.x += v1.x; acc.y += v1.y; acc.z += v1.z; acc.w += v1.w;
  }
  *(float4*)&sh[g][lc] = acc;
  __syncthreads();
  if (t < 128) {
    float total = 0.f;
#pragma unroll
    for (int gg = 0; gg < 8; ++gg) total += sh[gg][t];
    float di = dinv[i];
    out[(long)i * HID + t] = fmaxf(di * total + bias[t], 0.f);
  }
}

// ---------------- graph start offsets from sorted batch (no atomics) ----------------
__global__ void k_starts(const int* __restrict__ batch, int N, int* __restrict__ start) {
  int i = blockIdx.x * blockDim.x + threadIdx.x;
  int stride = gridDim.x * blockDim.x;
  for (; i < N; i += stride) {
    int g = batch[i];
    if (i == 0) {
      start[g] = 0;
    } else if (batch[i - 1] != g) {
      start[g] = i;
    }
  }
}

// back-fill empty graphs: start[g]==-1 -> start[g+1]
__global__ void k_fix_starts(int* __restrict__ start, int G, int N) {
  if (blockIdx.x == 0 && threadIdx.x == 0) {
    start[G] = N;
    for (int g = G - 1; g >= 0; --g)
      if (start[g] < 0) start[g] = start[g + 1];
  }
}

// ---------------- mean-pool partial sums (batch is sorted) ----------------
__global__ __launch_bounds__(128) void k_pool(const float* __restrict__ h,
                                              const int* __restrict__ batch,
                                              float* __restrict__ psum, int N) {
  __shared__ int bsh[POOL_CHUNK];
  int c = threadIdx.x;
  int start = blockIdx.x * POOL_CHUNK;
  int end = min(N, start + POOL_CHUNK);
  int len = end - start;
  if (len <= 0) return;
  for (int i = c; i < len; i += 128) bsh[i] = batch[start + i];
  __syncthreads();
  int cur = bsh[0];
  float acc = 0.f;
  for (int i = 0; i < len; ++i) {
    int g = bsh[i];
    if (g != cur) {
      atomicAdd(&psum[cur * HID + c], acc);
      acc = 0.f;
      cur = g;
    }
    acc += h[(long)(start + i) * HID + c];
  }
  atomicAdd(&psum[cur * HID + c], acc);
}

// ---------------- MLP head: one block per graph ----------------
__global__ __launch_bounds__(128) void k_head(const float* __restrict__ psum,
                                              const int* __restrict__ gstart,
                                              const float* __restrict__ fc1w,
                                              const float* __restrict__ fc1b,
                                              const float* __restrict__ fc2w,
                                              const float* __restrict__ fc2b,
                                              float* __restrict__ out, int G) {
  __shared__ float pooled[HID];
  __shared__ float z1[HID];
  int g = blockIdx.x;
  int c = threadIdx.x;
  float cn = fmaxf((float)(gstart[g + 1] - gstart[g]), 1.f);
  pooled[c] = psum[g * HID + c] / cn;
  __syncthreads();
  float a = fc1b[c];
#pragma unroll 8
  for (int k = 0; k < HID; ++k) a += pooled[k] * fc1w[k * HID + c];
  z1[c] = fmaxf(a, 0.f);
  __syncthreads();
  if (c < 16) {
    float o = fc2b[c];
#pragma unroll 8
    for (int k = 0; k < HID; ++k) o += z1[k] * fc2w[k * 16 + c];
    out[g * 16 + c] = o;
  }
}

extern "C" void kernel_launch(void* const* d_in, const int* in_sizes, int n_in,
                              void* d_out, int out_size, void* d_ws, size_t ws_size,
                              hipStream_t stream) {
  const float* x     = (const float*)d_in[0];
  const int*   ei    = (const int*)d_in[1];
  const int*   batch = (const int*)d_in[2];
  const float* w1    = (const float*)d_in[3];
  const float* b1    = (const float*)d_in[4];
  const float* w2    = (const float*)d_in[5];
  const float* b2    = (const float*)d_in[6];
  const float* w3    = (const float*)d_in[7];
  const float* b3    = (const float*)d_in[8];
  const float* fc1w  = (const float*)d_in[9];
  const float* fc1b  = (const float*)d_in[10];
  const float* fc2w  = (const float*)d_in[11];
  const float* fc2b  = (const float*)d_in[12];
  float* out = (float*)d_out;

  const int IN = in_sizes[3] / HID;   // 260
  const int N  = in_sizes[0] / IN;    // 100000
  const int E  = in_sizes[1] / 2;     // 3200000
  const int G  = out_size / 16;       // 64

  const int* srcp = ei;
  const int* dstp = ei + E;

  // ---- workspace carve (all 256B-aligned) ----
  char* wsp = (char*)d_ws;
  auto alloc = [&](size_t bytes) {
    char* p = wsp;
    wsp += (bytes + 255) & ~(size_t)255;
    return p;
  };
  int*   deg      = (int*)alloc((size_t)N * 4);
  int*   rowstart = (int*)alloc((size_t)N * 4);
  int*   bsum     = (int*)alloc(1024 * 4);
  int*   boff     = (int*)alloc(1024 * 4);
  int*   bhist    = (int*)alloc(NB * 4);
  int*   bstart   = (int*)alloc((NB + 1) * 4);
  int*   gcur     = (int*)alloc(NB * 4);
  int*   gstart   = (int*)alloc((size_t)(G + 1) * 4);
  float* dinv     = (float*)alloc((size_t)N * 4);
  float* psum     = (float*)alloc((size_t)G * HID * 4);
  int*   csr      = (int*)alloc((size_t)E * 4);
  float* bufA     = (float*)alloc((size_t)N * HID * 4);
  float* bufB     = (float*)alloc((size_t)N * HID * 4);
  // binned edge array (E x 8B) aliases bufA (N*HID*4 = 51.2MB >= 25.6MB):
  // fully consumed by k_bdeg/k_place before the first k_gemm writes bufA.
  unsigned long long* binned = (unsigned long long*)bufA;

  // ---- zero/init state (every call; buffers persist across graph replays) ----
  k_fill32<<<4, 256, 0, stream>>>((int*)psum, G * HID, 0);
  k_fill32<<<1, 128, 0, stream>>>(gstart, G + 1, -1);
  k_fill32<<<1, 256, 0, stream>>>(bhist, NB, 0);

  // ---- binned CSR build ----
  k_hist<<<512, 256, 0, stream>>>(dstp, E, N, bhist);
  k_bscan<<<1, 1, 0, stream>>>(bhist, bstart, gcur, E);
  k_scatter<<<512, 256, 0, stream>>>(srcp, dstp, E, N, binned, gcur);
  k_bdeg<<<NB, 256, 0, stream>>>(binned, bstart, N, deg);
  k_dinv<<<(N + 255) / 256, 256, 0, stream>>>(deg, dinv, N);

  int nb = (N + SCAN_CHUNK - 1) / SCAN_CHUNK;
  k_scan_block_sums<<<nb, 256, 0, stream>>>(deg, N, bsum);
  k_scan_offsets<<<1, 1, 0, stream>>>(bsum, nb, boff);
  k_scan_write<<<nb, 256, 0, stream>>>(deg, N, boff, rowstart);
  k_place<<<NB, 256, 0, stream>>>(binned, bstart, rowstart, N, csr);

  // ---- graph boundaries ----
  k_starts<<<256, 256, 0, stream>>>(batch, N, gstart);
  k_fix_starts<<<1, 1, 0, stream>>>(gstart, G, N);

  // ---- 3 GCN layers (GEMM epilogue pre-scales rows by dinv) ----
  int gblocks = (N + 127) / 128;
  k_gemm<<<gblocks, 256, 0, stream>>>(x, w1, dinv, bufA, N, IN);
  k_agg<<<N, 256, 0, stream>>>(bufA, dinv, rowstart, deg, csr, b1, bufB, N);

  k_gemm<<<gblocks, 256, 0, stream>>>(bufB, w2, dinv, bufA, N, HID);
  k_agg<<<N, 256, 0, stream>>>(bufA, dinv, rowstart, deg, csr, b2, bufB, N);

  k_gemm<<<gblocks, 256, 0, stream>>>(bufB, w3, dinv, bufA, N, HID);
  k_agg<<<N, 256, 0, stream>>>(bufA, dinv, rowstart, deg, csr, b3, bufB, N);

  // ---- pool + head ----
  int pblocks = (N + POOL_CHUNK - 1) / POOL_CHUNK;
  k_pool<<<pblocks, 128, 0, stream>>>(bufB, batch, psum, N);
  k_head<<<G, 128, 0, stream>>>(psum, gstart, fc1w, fc1b, fc2w, fc2b, out, G);
}

// Round 5
// 994.553 us; speedup vs baseline: 1.9868x; 1.1858x over previous
//
#include <hip/hip_runtime.h>

#define HID 128
#define SCAN_CHUNK 1024
#define POOL_CHUNK 512

// binned CSR build params
#define NB 256      // buckets over dst space (monotone: b = dst*NB/N)
#define BW 400      // max bucket width (ceil(100000/256)=391)
#define DEPTH 24    // LDS staging depth per bucket per round
#define CH 2048     // edges per block per round

// ---------------- bf16 helpers (RNE pack, shift unpack) ----------------
__device__ inline float blo(unsigned u) { return __uint_as_float(u << 16); }
__device__ inline float bhi(unsigned u) { return __uint_as_float(u & 0xffff0000u); }
__device__ inline unsigned rne16(float x) {
  unsigned u = __float_as_uint(x);
  return (u + 0x7fffu + ((u >> 16) & 1u)) >> 16;
}
__device__ inline unsigned pk2(float a, float b) { return (rne16(b) << 16) | rne16(a); }

// ---------------- utility: fill int buffers ----------------
__global__ void k_fill32(int* __restrict__ p, int n, int val) {
  int i = blockIdx.x * blockDim.x + threadIdx.x;
  int stride = gridDim.x * blockDim.x;
  for (; i < n; i += stride) p[i] = val;
}

// ---------------- bucket histogram (LDS-staged) ----------------
__global__ __launch_bounds__(256) void k_hist(const int* __restrict__ dst, int E, int N,
                                              int* __restrict__ bhist) {
  __shared__ int h[NB];
  int t = threadIdx.x;
  h[t] = 0;
  __syncthreads();
  int i = blockIdx.x * blockDim.x + t;
  int stride = gridDim.x * blockDim.x;
  for (; i < E; i += stride) {
    int b = (int)(((long long)dst[i] * NB) / N);
    atomicAdd(&h[b], 1);
  }
  __syncthreads();
  if (h[t]) atomicAdd(&bhist[t], h[t]);
}

__global__ void k_bscan(const int* __restrict__ bhist, int* __restrict__ bstart,
                        int* __restrict__ gcur, int E) {
  if (blockIdx.x == 0 && threadIdx.x == 0) {
    int run = 0;
    for (int b = 0; b < NB; ++b) { bstart[b] = run; gcur[b] = run; run += bhist[b]; }
    bstart[NB] = run; // == E
  }
}

// ---------------- LDS-staged scatter into bucket-major order ----------------
__global__ __launch_bounds__(256) void k_scatter(const int* __restrict__ src,
                                                 const int* __restrict__ dst,
                                                 int E, int N,
                                                 unsigned long long* __restrict__ binned,
                                                 int* __restrict__ gcur) {
  __shared__ unsigned long long buf[NB][DEPTH]; // 48 KB
  __shared__ int cnt[NB];
  int t = threadIdx.x;
  long cover = (long)gridDim.x * CH;
  int nround = (int)((E + cover - 1) / cover);
  for (int r = 0; r < nround; ++r) {
    cnt[t] = 0;
    __syncthreads();
    long base = (long)r * cover + (long)blockIdx.x * CH;
#pragma unroll
    for (int k = 0; k < CH / 256; ++k) {
      long i = base + k * 256 + t;
      if (i < E) {
        int s = src[i], d = dst[i];
        int b = (int)(((long long)d * NB) / N);
        unsigned long long pack =
            ((unsigned long long)(unsigned)d << 32) | (unsigned)s;
        int slot = atomicAdd(&cnt[b], 1);
        if (slot < DEPTH) buf[b][slot] = pack;
        else { int g = atomicAdd(&gcur[b], 1); binned[g] = pack; } // rare spill
      }
    }
    __syncthreads();
    // flush: thread t owns bucket t
    {
      int c = cnt[t];
      if (c > DEPTH) c = DEPTH;
      if (c > 0) {
        int g = atomicAdd(&gcur[t], c);
        for (int k = 0; k < c; ++k) binned[g + k] = buf[t][k];
      }
    }
    __syncthreads();
  }
}

// ---------------- per-bucket degree histogram ----------------
__global__ __launch_bounds__(256) void k_bdeg(const unsigned long long* __restrict__ binned,
                                              const int* __restrict__ bstart, int N,
                                              int* __restrict__ deg) {
  __shared__ int hist[BW];
  int b = blockIdx.x;
  int t = threadIdx.x;
  int d0 = (int)(((long long)b * N + NB - 1) / NB);
  int d1 = (int)(((long long)(b + 1) * N + NB - 1) / NB);
  if (d1 > N) d1 = N;
  int W = d1 - d0;
  for (int w = t; w < W; w += 256) hist[w] = 0;
  __syncthreads();
  int s = bstart[b], e = bstart[b + 1];
  for (int i = s + t; i < e; i += 256) {
    int d = (int)(binned[i] >> 32);
    atomicAdd(&hist[d - d0], 1);
  }
  __syncthreads();
  for (int w = t; w < W; w += 256) deg[d0 + w] = hist[w];
}

__global__ void k_dinv(const int* __restrict__ deg, float* __restrict__ dinv, int N) {
  int i = blockIdx.x * blockDim.x + threadIdx.x;
  int stride = gridDim.x * blockDim.x;
  for (; i < N; i += stride) dinv[i] = rsqrtf((float)(deg[i] + 1)); // +1 = self loop
}

// ---------------- exclusive scan of deg -> rowstart (3 kernels) ----------------
__global__ void k_scan_block_sums(const int* __restrict__ deg, int N, int* __restrict__ bsum) {
  __shared__ int sh[256];
  int base = blockIdx.x * SCAN_CHUNK;
  int t = threadIdx.x;
  int s = 0;
#pragma unroll
  for (int j = 0; j < 4; ++j) {
    int idx = base + t * 4 + j;
    if (idx < N) s += deg[idx];
  }
  sh[t] = s;
  __syncthreads();
  for (int off = 128; off > 0; off >>= 1) {
    if (t < off) sh[t] += sh[t + off];
    __syncthreads();
  }
  if (t == 0) bsum[blockIdx.x] = sh[0];
}

__global__ void k_scan_offsets(const int* __restrict__ bsum, int nb, int* __restrict__ boff) {
  if (blockIdx.x == 0 && threadIdx.x == 0) {
    int run = 0;
    for (int i = 0; i < nb; ++i) { boff[i] = run; run += bsum[i]; }
  }
}

__global__ void k_scan_write(const int* __restrict__ deg, int N,
                             const int* __restrict__ boff, int* __restrict__ rowstart) {
  __shared__ int sh[256];
  int base = blockIdx.x * SCAN_CHUNK;
  int t = threadIdx.x;
  int v[4];
  int s = 0;
#pragma unroll
  for (int j = 0; j < 4; ++j) {
    int idx = base + t * 4 + j;
    v[j] = (idx < N) ? deg[idx] : 0;
    s += v[j];
  }
  sh[t] = s;
  __syncthreads();
  for (int off = 1; off < 256; off <<= 1) {
    int x = 0;
    if (t >= off) x = sh[t - off];
    __syncthreads();
    sh[t] += x;
    __syncthreads();
  }
  int excl = sh[t] - s;
  int run = boff[blockIdx.x] + excl;
#pragma unroll
  for (int j = 0; j < 4; ++j) {
    int idx = base + t * 4 + j;
    if (idx < N) rowstart[idx] = run;
    run += v[j];
  }
}

// ---------------- per-bucket CSR placement with LDS cursors ----------------
__global__ __launch_bounds__(256) void k_place(const unsigned long long* __restrict__ binned,
                                               const int* __restrict__ bstart,
                                               const int* __restrict__ rowstart, int N,
                                               int* __restrict__ csr) {
  __shared__ int cur[BW];
  int b = blockIdx.x;
  int t = threadIdx.x;
  int d0 = (int)(((long long)b * N + NB - 1) / NB);
  int d1 = (int)(((long long)(b + 1) * N + NB - 1) / NB);
  if (d1 > N) d1 = N;
  int W = d1 - d0;
  for (int w = t; w < W; w += 256) cur[w] = 0;
  __syncthreads();
  int s = bstart[b], e = bstart[b + 1];
  for (int i = s + t; i < e; i += 256) {
    unsigned long long p = binned[i];
    int d = (int)(p >> 32);
    int sn = (int)(p & 0xffffffffu);
    int pos = rowstart[d] + atomicAdd(&cur[d - d0], 1);
    csr[pos] = sn;
  }
}

// ---------------- dense GEMM: Cbf16[N][128] = dscale(row) * (A[N][K] @ W[K][128]) --
// block = 256 threads, tile = 128 rows x 128 cols, K-tile = 16, 8x8 per thread
// A is f32 (ABF16=false, layer 1) or bf16-packed (ABF16=true, layers 2/3).
template <bool ABF16>
__global__ __launch_bounds__(256) void k_gemm(const void* __restrict__ Ap,
                                              const float* __restrict__ W,
                                              const float* __restrict__ dscale,
                                              unsigned* __restrict__ Cu, int N, int K) {
  __shared__ float As[16][132];   // transposed A tile: As[k][row]
  __shared__ float Ws[16][128];   // Ws[k][col]
  int t = threadIdx.x;
  int tx = t & 15;    // col group: cols tx*8 .. tx*8+7
  int ty = t >> 4;    // row group: rows ty*8 .. ty*8+7
  int r0 = blockIdx.x * 128;

  float4 acc0[8], acc1[8];
#pragma unroll
  for (int r = 0; r < 8; ++r) {
    acc0[r] = make_float4(0.f, 0.f, 0.f, 0.f);
    acc1[r] = make_float4(0.f, 0.f, 0.f, 0.f);
  }

  for (int kt = 0; kt < K; kt += 16) {
    // ---- stage A tile 128x16 (transposed into As[k][row]) ----
#pragma unroll
    for (int p = 0; p < 2; ++p) {
      int idx = t + p * 256;
      int row = idx >> 2;           // 0..127
      int kq = (idx & 3) * 4;       // 0,4,8,12
      int gr = r0 + row;
      int kb = kt + kq;
      float a0 = 0.f, a1 = 0.f, a2 = 0.f, a3 = 0.f;
      if (ABF16) {
        if (gr < N) {  // K=128 always full
          const unsigned* Au = (const unsigned*)Ap;
          uint2 u = *(const uint2*)&Au[(long)gr * (K >> 1) + (kb >> 1)];
          a0 = blo(u.x); a1 = bhi(u.x); a2 = blo(u.y); a3 = bhi(u.y);
        }
      } else {
        const float* A = (const float*)Ap;
        if (gr < N && kb < K) {     // K % 4 == 0
          float4 av = *(const float4*)&A[(long)gr * K + kb];
          a0 = av.x; a1 = av.y; a2 = av.z; a3 = av.w;
        }
      }
      As[kq + 0][row] = a0;
      As[kq + 1][row] = a1;
      As[kq + 2][row] = a2;
      As[kq + 3][row] = a3;
    }
    // ---- stage W tile 16x128 ----
#pragma unroll
    for (int p = 0; p < 2; ++p) {
      int idx = t + p * 256;
      int wr = idx >> 5;            // 0..15
      int wc = (idx & 31) * 4;      // 0..124
      int gk = kt + wr;
      float4 wv = make_float4(0.f, 0.f, 0.f, 0.f);
      if (gk < K) wv = *(const float4*)&W[(long)gk * HID + wc];
      *(float4*)&Ws[wr][wc] = wv;
    }
    __syncthreads();
#pragma unroll
    for (int kk = 0; kk < 16; ++kk) {
      float4 a0 = *(float4*)&As[kk][ty * 8];
      float4 a1 = *(float4*)&As[kk][ty * 8 + 4];
      float4 w0 = *(float4*)&Ws[kk][tx * 8];
      float4 w1 = *(float4*)&Ws[kk][tx * 8 + 4];
      float ar[8] = {a0.x, a0.y, a0.z, a0.w, a1.x, a1.y, a1.z, a1.w};
#pragma unroll
      for (int r = 0; r < 8; ++r) {
        float a = ar[r];
        acc0[r].x += a * w0.x; acc0[r].y += a * w0.y;
        acc0[r].z += a * w0.z; acc0[r].w += a * w0.w;
        acc1[r].x += a * w1.x; acc1[r].y += a * w1.y;
        acc1[r].z += a * w1.z; acc1[r].w += a * w1.w;
      }
    }
    __syncthreads();
  }
#pragma unroll
  for (int r = 0; r < 8; ++r) {
    int gr = r0 + ty * 8 + r;
    if (gr < N) {
      float s = dscale[gr];
      uint4 o;
      o.x = pk2(acc0[r].x * s, acc0[r].y * s);
      o.y = pk2(acc0[r].z * s, acc0[r].w * s);
      o.z = pk2(acc1[r].x * s, acc1[r].y * s);
      o.w = pk2(acc1[r].z * s, acc1[r].w * s);
      *(uint4*)&Cu[(long)gr * 64 + tx * 4] = o;
    }
  }
}

// ---------------- pull aggregation + bias + relu (bf16 rows) ----------------
// T is bf16-packed, pre-scaled by dinv:
// out[i][c] = relu( dinv[i] * ( T[i][c] + sum_nbr T[s][c] ) + b[c] ), packed bf16
// block = 256 threads: 8 neighbor-groups x 32 lanes (each lane = 4 channels, uint2)
__global__ __launch_bounds__(256) void k_agg(const uint2* __restrict__ T,   // [N][32]
                                             const float* __restrict__ dinv,
                                             const int* __restrict__ rowstart,
                                             const int* __restrict__ deg,
                                             const int* __restrict__ csr,
                                             const float* __restrict__ bias,
                                             unsigned* __restrict__ outu,   // [N][64]
                                             int N) {
  __shared__ float sh[8][128];
  int i = blockIdx.x;
  int t = threadIdx.x;
  int g = t >> 5;          // neighbor group 0..7
  int lane = t & 31;       // channel quad: channels lane*4 .. lane*4+3

  float4 acc = make_float4(0.f, 0.f, 0.f, 0.f);
  if (g == 0) {
    uint2 u = T[(long)i * 32 + lane];            // self-loop term (pre-scaled)
    acc.x = blo(u.x); acc.y = bhi(u.x); acc.z = blo(u.y); acc.w = bhi(u.y);
  }

  int s0 = rowstart[i];
  int d = deg[i];
  int j = g;
  for (; j + 8 < d; j += 16) {
    int s1 = csr[s0 + j];
    int s2 = csr[s0 + j + 8];
    uint2 u1 = T[(long)s1 * 32 + lane];
    uint2 u2 = T[(long)s2 * 32 + lane];
    acc.x += blo(u1.x) + blo(u2.x);
    acc.y += bhi(u1.x) + bhi(u2.x);
    acc.z += blo(u1.y) + blo(u2.y);
    acc.w += bhi(u1.y) + bhi(u2.y);
  }
  if (j < d) {
    int s1 = csr[s0 + j];
    uint2 u1 = T[(long)s1 * 32 + lane];
    acc.x += blo(u1.x); acc.y += bhi(u1.x); acc.z += blo(u1.y); acc.w += bhi(u1.y);
  }
  *(float4*)&sh[g][lane * 4] = acc;
  __syncthreads();
  if (t < 128) {
    float total = 0.f;
#pragma unroll
    for (int gg = 0; gg < 8; ++gg) total += sh[gg][t];
    float v = fmaxf(dinv[i] * total + bias[t], 0.f);
    float w = __shfl_xor(v, 1);
    if (!(t & 1)) outu[(long)i * 64 + (t >> 1)] = pk2(v, w);
  }
}

// ---------------- graph start offsets from sorted batch (no atomics) ----------------
__global__ void k_starts(const int* __restrict__ batch, int N, int* __restrict__ start) {
  int i = blockIdx.x * blockDim.x + threadIdx.x;
  int stride = gridDim.x * blockDim.x;
  for (; i < N; i += stride) {
    int g = batch[i];
    if (i == 0) {
      start[g] = 0;
    } else if (batch[i - 1] != g) {
      start[g] = i;
    }
  }
}

// back-fill empty graphs: start[g]==-1 -> start[g+1]
__global__ void k_fix_starts(int* __restrict__ start, int G, int N) {
  if (blockIdx.x == 0 && threadIdx.x == 0) {
    start[G] = N;
    for (int g = G - 1; g >= 0; --g)
      if (start[g] < 0) start[g] = start[g + 1];
  }
}

// ---------------- mean-pool partial sums (batch is sorted, h is bf16) ----------------
__global__ __launch_bounds__(128) void k_pool(const unsigned* __restrict__ hu, // [N][64]
                                              const int* __restrict__ batch,
                                              float* __restrict__ psum, int N) {
  __shared__ int bsh[POOL_CHUNK];
  int c = threadIdx.x;
  int start = blockIdx.x * POOL_CHUNK;
  int end = min(N, start + POOL_CHUNK);
  int len = end - start;
  if (len <= 0) return;
  for (int i = c; i < len; i += 128) bsh[i] = batch[start + i];
  __syncthreads();
  int cur = bsh[0];
  float acc = 0.f;
  int half = c >> 1;
  int odd = c & 1;
  for (int i = 0; i < len; ++i) {
    int g = bsh[i];
    if (g != cur) {
      atomicAdd(&psum[cur * HID + c], acc);
      acc = 0.f;
      cur = g;
    }
    unsigned u = hu[(long)(start + i) * 64 + half];
    acc += odd ? bhi(u) : blo(u);
  }
  atomicAdd(&psum[cur * HID + c], acc);
}

// ---------------- MLP head: one block per graph ----------------
__global__ __launch_bounds__(128) void k_head(const float* __restrict__ psum,
                                              const int* __restrict__ gstart,
                                              const float* __restrict__ fc1w,
                                              const float* __restrict__ fc1b,
                                              const float* __restrict__ fc2w,
                                              const float* __restrict__ fc2b,
                                              float* __restrict__ out, int G) {
  __shared__ float pooled[HID];
  __shared__ float z1[HID];
  int g = blockIdx.x;
  int c = threadIdx.x;
  float cn = fmaxf((float)(gstart[g + 1] - gstart[g]), 1.f);
  pooled[c] = psum[g * HID + c] / cn;
  __syncthreads();
  float a = fc1b[c];
#pragma unroll 8
  for (int k = 0; k < HID; ++k) a += pooled[k] * fc1w[k * HID + c];
  z1[c] = fmaxf(a, 0.f);
  __syncthreads();
  if (c < 16) {
    float o = fc2b[c];
#pragma unroll 8
    for (int k = 0; k < HID; ++k) o += z1[k] * fc2w[k * 16 + c];
    out[g * 16 + c] = o;
  }
}

extern "C" void kernel_launch(void* const* d_in, const int* in_sizes, int n_in,
                              void* d_out, int out_size, void* d_ws, size_t ws_size,
                              hipStream_t stream) {
  const float* x     = (const float*)d_in[0];
  const int*   ei    = (const int*)d_in[1];
  const int*   batch = (const int*)d_in[2];
  const float* w1    = (const float*)d_in[3];
  const float* b1    = (const float*)d_in[4];
  const float* w2    = (const float*)d_in[5];
  const float* b2    = (const float*)d_in[6];
  const float* w3    = (const float*)d_in[7];
  const float* b3    = (const float*)d_in[8];
  const float* fc1w  = (const float*)d_in[9];
  const float* fc1b  = (const float*)d_in[10];
  const float* fc2w  = (const float*)d_in[11];
  const float* fc2b  = (const float*)d_in[12];
  float* out = (float*)d_out;

  const int IN = in_sizes[3] / HID;   // 260
  const int N  = in_sizes[0] / IN;    // 100000
  const int E  = in_sizes[1] / 2;     // 3200000
  const int G  = out_size / 16;       // 64

  const int* srcp = ei;
  const int* dstp = ei + E;

  // ---- workspace carve (all 256B-aligned) ----
  char* wsp = (char*)d_ws;
  auto alloc = [&](size_t bytes) {
    char* p = wsp;
    wsp += (bytes + 255) & ~(size_t)255;
    return p;
  };
  int*   deg      = (int*)alloc((size_t)N * 4);
  int*   rowstart = (int*)alloc((size_t)N * 4);
  int*   bsum     = (int*)alloc(1024 * 4);
  int*   boff     = (int*)alloc(1024 * 4);
  int*   bhist    = (int*)alloc(NB * 4);
  int*   bstart   = (int*)alloc((NB + 1) * 4);
  int*   gcur     = (int*)alloc(NB * 4);
  int*   gstart   = (int*)alloc((size_t)(G + 1) * 4);
  float* dinv     = (float*)alloc((size_t)N * 4);
  float* psum     = (float*)alloc((size_t)G * HID * 4);
  int*   csr      = (int*)alloc((size_t)E * 4);
  unsigned* bufA  = (unsigned*)alloc((size_t)N * 64 * 4);  // bf16 [N][128] packed
  unsigned* bufB  = (unsigned*)alloc((size_t)N * 64 * 4);  // bf16 [N][128] packed
  // binned edge array (E x 8B = 25.6MB) aliases bufA (N*64*4 = 25.6MB):
  // fully consumed by k_bdeg/k_place before the first k_gemm writes bufA.
  unsigned long long* binned = (unsigned long long*)bufA;

  // ---- zero/init state (every call; buffers persist across graph replays) ----
  k_fill32<<<4, 256, 0, stream>>>((int*)psum, G * HID, 0);
  k_fill32<<<1, 128, 0, stream>>>(gstart, G + 1, -1);
  k_fill32<<<1, 256, 0, stream>>>(bhist, NB, 0);

  // ---- binned CSR build ----
  k_hist<<<512, 256, 0, stream>>>(dstp, E, N, bhist);
  k_bscan<<<1, 1, 0, stream>>>(bhist, bstart, gcur, E);
  k_scatter<<<512, 256, 0, stream>>>(srcp, dstp, E, N, binned, gcur);
  k_bdeg<<<NB, 256, 0, stream>>>(binned, bstart, N, deg);
  k_dinv<<<(N + 255) / 256, 256, 0, stream>>>(deg, dinv, N);

  int nb = (N + SCAN_CHUNK - 1) / SCAN_CHUNK;
  k_scan_block_sums<<<nb, 256, 0, stream>>>(deg, N, bsum);
  k_scan_offsets<<<1, 1, 0, stream>>>(bsum, nb, boff);
  k_scan_write<<<nb, 256, 0, stream>>>(deg, N, boff, rowstart);
  k_place<<<NB, 256, 0, stream>>>(binned, bstart, rowstart, N, csr);

  // ---- graph boundaries ----
  k_starts<<<256, 256, 0, stream>>>(batch, N, gstart);
  k_fix_starts<<<1, 1, 0, stream>>>(gstart, G, N);

  // ---- 3 GCN layers (GEMM epilogue pre-scales rows by dinv, packs bf16) ----
  int gblocks = (N + 127) / 128;
  k_gemm<false><<<gblocks, 256, 0, stream>>>(x, w1, dinv, bufA, N, IN);
  k_agg<<<N, 256, 0, stream>>>((const uint2*)bufA, dinv, rowstart, deg, csr, b1, bufB, N);

  k_gemm<true><<<gblocks, 256, 0, stream>>>(bufB, w2, dinv, bufA, N, HID);
  k_agg<<<N, 256, 0, stream>>>((const uint2*)bufA, dinv, rowstart, deg, csr, b2, bufB, N);

  k_gemm<true><<<gblocks, 256, 0, stream>>>(bufB, w3, dinv, bufA, N, HID);
  k_agg<<<N, 256, 0, stream>>>((const uint2*)bufA, dinv, rowstart, deg, csr, b3, bufB, N);

  // ---- pool + head ----
  int pblocks = (N + POOL_CHUNK - 1) / POOL_CHUNK;
  k_pool<<<pblocks, 128, 0, stream>>>(bufB, batch, psum, N);
  k_head<<<G, 128, 0, stream>>>(psum, gstart, fc1w, fc1b, fc2w, fc2b, out, G);
}

// Round 6
// 881.093 us; speedup vs baseline: 2.2426x; 1.1288x over previous
//
#include <hip/hip_runtime.h>

#define HID 128
#define SCAN_CHUNK 1024
#define POOL_CHUNK 512

// binned CSR build params
#define NB 256
#define BW 400
#define DEPTH 24
#define CH 2048

typedef __attribute__((ext_vector_type(8))) short bf16x8;
typedef __attribute__((ext_vector_type(4))) float f32x4;

// ---------------- bf16 helpers (RNE pack, shift unpack) ----------------
__device__ inline float blo(unsigned u) { return __uint_as_float(u << 16); }
__device__ inline float bhi(unsigned u) { return __uint_as_float(u & 0xffff0000u); }
__device__ inline unsigned rne16(float x) {
  unsigned u = __float_as_uint(x);
  return (u + 0x7fffu + ((u >> 16) & 1u)) >> 16;
}
__device__ inline unsigned pk2(float a, float b) { return (rne16(b) << 16) | rne16(a); }

// ---------------- utility: fill int buffers ----------------
__global__ void k_fill32(int* __restrict__ p, int n, int val) {
  int i = blockIdx.x * blockDim.x + threadIdx.x;
  int stride = gridDim.x * blockDim.x;
  for (; i < n; i += stride) p[i] = val;
}

// ---------------- weight transpose + bf16 pack: Wt[c][k] from W[k][c] ----------
// Wt is u32 [128][KP2] (bf16 pair per u32), zero-padded for k >= K
__global__ void k_prep_w(const float* __restrict__ W, unsigned* __restrict__ Wt,
                         int K, int KP2) {
  int idx = blockIdx.x * 256 + threadIdx.x;
  int total = 128 * KP2;
  if (idx >= total) return;
  int c = idx / KP2, kk = idx - c * KP2;
  int k0 = kk * 2, k1 = k0 + 1;
  float v0 = (k0 < K) ? W[(long)k0 * 128 + c] : 0.f;
  float v1 = (k1 < K) ? W[(long)k1 * 128 + c] : 0.f;
  Wt[idx] = pk2(v0, v1);
}

// ---------------- bucket histogram (LDS-staged) ----------------
__global__ __launch_bounds__(256) void k_hist(const int* __restrict__ dst, int E, int N,
                                              int* __restrict__ bhist) {
  __shared__ int h[NB];
  int t = threadIdx.x;
  h[t] = 0;
  __syncthreads();
  int i = blockIdx.x * blockDim.x + t;
  int stride = gridDim.x * blockDim.x;
  for (; i < E; i += stride) {
    int b = (int)(((long long)dst[i] * NB) / N);
    atomicAdd(&h[b], 1);
  }
  __syncthreads();
  if (h[t]) atomicAdd(&bhist[t], h[t]);
}

__global__ void k_bscan(const int* __restrict__ bhist, int* __restrict__ bstart,
                        int* __restrict__ gcur, int E) {
  if (blockIdx.x == 0 && threadIdx.x == 0) {
    int run = 0;
    for (int b = 0; b < NB; ++b) { bstart[b] = run; gcur[b] = run; run += bhist[b]; }
    bstart[NB] = run; // == E
  }
}

// ---------------- LDS-staged scatter into bucket-major order ----------------
__global__ __launch_bounds__(256) void k_scatter(const int* __restrict__ src,
                                                 const int* __restrict__ dst,
                                                 int E, int N,
                                                 unsigned long long* __restrict__ binned,
                                                 int* __restrict__ gcur) {
  __shared__ unsigned long long buf[NB][DEPTH]; // 48 KB
  __shared__ int cnt[NB];
  int t = threadIdx.x;
  long cover = (long)gridDim.x * CH;
  int nround = (int)((E + cover - 1) / cover);
  for (int r = 0; r < nround; ++r) {
    cnt[t] = 0;
    __syncthreads();
    long base = (long)r * cover + (long)blockIdx.x * CH;
#pragma unroll
    for (int k = 0; k < CH / 256; ++k) {
      long i = base + k * 256 + t;
      if (i < E) {
        int s = src[i], d = dst[i];
        int b = (int)(((long long)d * NB) / N);
        unsigned long long pack =
            ((unsigned long long)(unsigned)d << 32) | (unsigned)s;
        int slot = atomicAdd(&cnt[b], 1);
        if (slot < DEPTH) buf[b][slot] = pack;
        else { int g = atomicAdd(&gcur[b], 1); binned[g] = pack; } // rare spill
      }
    }
    __syncthreads();
    {
      int c = cnt[t];
      if (c > DEPTH) c = DEPTH;
      if (c > 0) {
        int g = atomicAdd(&gcur[t], c);
        for (int k = 0; k < c; ++k) binned[g + k] = buf[t][k];
      }
    }
    __syncthreads();
  }
}

// ---------------- per-bucket degree histogram ----------------
__global__ __launch_bounds__(256) void k_bdeg(const unsigned long long* __restrict__ binned,
                                              const int* __restrict__ bstart, int N,
                                              int* __restrict__ deg) {
  __shared__ int hist[BW];
  int b = blockIdx.x;
  int t = threadIdx.x;
  int d0 = (int)(((long long)b * N + NB - 1) / NB);
  int d1 = (int)(((long long)(b + 1) * N + NB - 1) / NB);
  if (d1 > N) d1 = N;
  int W = d1 - d0;
  for (int w = t; w < W; w += 256) hist[w] = 0;
  __syncthreads();
  int s = bstart[b], e = bstart[b + 1];
  for (int i = s + t; i < e; i += 256) {
    int d = (int)(binned[i] >> 32);
    atomicAdd(&hist[d - d0], 1);
  }
  __syncthreads();
  for (int w = t; w < W; w += 256) deg[d0 + w] = hist[w];
}

__global__ void k_dinv(const int* __restrict__ deg, float* __restrict__ dinv, int N) {
  int i = blockIdx.x * blockDim.x + threadIdx.x;
  int stride = gridDim.x * blockDim.x;
  for (; i < N; i += stride) dinv[i] = rsqrtf((float)(deg[i] + 1)); // +1 = self loop
}

// ---------------- exclusive scan of deg -> rowstart ----------------
__global__ void k_scan_block_sums(const int* __restrict__ deg, int N, int* __restrict__ bsum) {
  __shared__ int sh[256];
  int base = blockIdx.x * SCAN_CHUNK;
  int t = threadIdx.x;
  int s = 0;
#pragma unroll
  for (int j = 0; j < 4; ++j) {
    int idx = base + t * 4 + j;
    if (idx < N) s += deg[idx];
  }
  sh[t] = s;
  __syncthreads();
  for (int off = 128; off > 0; off >>= 1) {
    if (t < off) sh[t] += sh[t + off];
    __syncthreads();
  }
  if (t == 0) bsum[blockIdx.x] = sh[0];
}

__global__ void k_scan_offsets(const int* __restrict__ bsum, int nb, int* __restrict__ boff) {
  if (blockIdx.x == 0 && threadIdx.x == 0) {
    int run = 0;
    for (int i = 0; i < nb; ++i) { boff[i] = run; run += bsum[i]; }
  }
}

__global__ void k_scan_write(const int* __restrict__ deg, int N,
                             const int* __restrict__ boff, int* __restrict__ rowstart) {
  __shared__ int sh[256];
  int base = blockIdx.x * SCAN_CHUNK;
  int t = threadIdx.x;
  int v[4];
  int s = 0;
#pragma unroll
  for (int j = 0; j < 4; ++j) {
    int idx = base + t * 4 + j;
    v[j] = (idx < N) ? deg[idx] : 0;
    s += v[j];
  }
  sh[t] = s;
  __syncthreads();
  for (int off = 1; off < 256; off <<= 1) {
    int x = 0;
    if (t >= off) x = sh[t - off];
    __syncthreads();
    sh[t] += x;
    __syncthreads();
  }
  int excl = sh[t] - s;
  int run = boff[blockIdx.x] + excl;
#pragma unroll
  for (int j = 0; j < 4; ++j) {
    int idx = base + t * 4 + j;
    if (idx < N) rowstart[idx] = run;
    run += v[j];
  }
}

// ---------------- per-bucket CSR placement with LDS cursors ----------------
__global__ __launch_bounds__(256) void k_place(const unsigned long long* __restrict__ binned,
                                               const int* __restrict__ bstart,
                                               const int* __restrict__ rowstart, int N,
                                               int* __restrict__ csr) {
  __shared__ int cur[BW];
  int b = blockIdx.x;
  int t = threadIdx.x;
  int d0 = (int)(((long long)b * N + NB - 1) / NB);
  int d1 = (int)(((long long)(b + 1) * N + NB - 1) / NB);
  if (d1 > N) d1 = N;
  int W = d1 - d0;
  for (int w = t; w < W; w += 256) cur[w] = 0;
  __syncthreads();
  int s = bstart[b], e = bstart[b + 1];
  for (int i = s + t; i < e; i += 256) {
    unsigned long long p = binned[i];
    int d = (int)(p >> 32);
    int sn = (int)(p & 0xffffffffu);
    int pos = rowstart[d] + atomicAdd(&cur[d - d0], 1);
    csr[pos] = sn;
  }
}

// ============ MFMA GEMM, layers 2/3: Cbf16 = dinv(row)*(Abf16[N][128] @ W[128][128]) ==
// No LDS. Block = 256 (4 waves); wave computes 32 rows x 128 cols.
// A: u32 [N][64] bf16-packed. Wt: u32 [128][64] (Wt[c][k] bf16, k-packed).
__global__ __launch_bounds__(256) void k_gemm_mf(const unsigned* __restrict__ A,
                                                 const unsigned* __restrict__ Wt,
                                                 const float* __restrict__ dscale,
                                                 unsigned* __restrict__ Cu, int N) {
  int t = threadIdx.x;
  int w = t >> 6;
  int l = t & 63;
  int lr = l & 15;   // frag row (A) / frag col (B, C)
  int kg = l >> 4;   // k-group 0..3
  int wr0 = blockIdx.x * 128 + w * 32;

  f32x4 acc[2][8];
#pragma unroll
  for (int rt = 0; rt < 2; ++rt)
#pragma unroll
    for (int f = 0; f < 8; ++f) acc[rt][f] = (f32x4){0.f, 0.f, 0.f, 0.f};

  int r0 = wr0 + lr, r1 = wr0 + 16 + lr;
#pragma unroll
  for (int kt = 0; kt < 4; ++kt) {
    int ko = kt * 16 + kg * 4;  // u32 offset within row (16B aligned)
    bf16x8 a0 = {}, a1 = {};
    if (r0 < N) a0 = *(const bf16x8*)&A[(long)r0 * 64 + ko];
    if (r1 < N) a1 = *(const bf16x8*)&A[(long)r1 * 64 + ko];
#pragma unroll
    for (int f = 0; f < 8; ++f) {
      bf16x8 b = *(const bf16x8*)&Wt[(f * 16 + lr) * 64 + ko];
      acc[0][f] = __builtin_amdgcn_mfma_f32_16x16x32_bf16(a0, b, acc[0][f], 0, 0, 0);
      acc[1][f] = __builtin_amdgcn_mfma_f32_16x16x32_bf16(a1, b, acc[1][f], 0, 0, 0);
    }
  }
#pragma unroll
  for (int rt = 0; rt < 2; ++rt) {
#pragma unroll
    for (int reg = 0; reg < 4; ++reg) {
      int row = wr0 + rt * 16 + kg * 4 + reg;
      float ds = (row < N) ? dscale[row] : 0.f;
#pragma unroll
      for (int f = 0; f < 8; ++f) {
        float v = acc[rt][f][reg] * ds;
        float pv = __shfl_xor(v, 1);
        if (!(l & 1) && row < N)
          Cu[(long)row * 64 + ((f * 16 + lr) >> 1)] = pk2(v, pv);
      }
    }
  }
}

// ============ MFMA GEMM, layer 1: Cbf16 = dinv(row)*(x[N][260] @ W1[260][128]) ======
// x is f32, converted to bf16 in-flight. Wt1: u32 [128][144] (K padded 260->288).
__global__ __launch_bounds__(256) void k_gemm1_mf(const float* __restrict__ X,
                                                  const unsigned* __restrict__ Wt,
                                                  const float* __restrict__ dscale,
                                                  unsigned* __restrict__ Cu, int N, int K) {
  int t = threadIdx.x;
  int w = t >> 6;
  int l = t & 63;
  int lr = l & 15;
  int kg = l >> 4;
  int wr0 = blockIdx.x * 128 + w * 32;

  f32x4 acc[2][8];
#pragma unroll
  for (int rt = 0; rt < 2; ++rt)
#pragma unroll
    for (int f = 0; f < 8; ++f) acc[rt][f] = (f32x4){0.f, 0.f, 0.f, 0.f};

  int r0 = wr0 + lr, r1 = wr0 + 16 + lr;
  int nkt = (K + 31) / 32;  // 9 for K=260
  for (int kt = 0; kt < nkt; ++kt) {
    int kb = kt * 32 + kg * 8;
    bf16x8 a0 = {}, a1 = {};
    if (kb + 7 < K) {
      if (r0 < N) {
        const float* p = &X[(long)r0 * K + kb];
        float4 u = *(const float4*)p, v = *(const float4*)(p + 4);
        union { uint4 q; bf16x8 b; } cv;
        cv.q.x = pk2(u.x, u.y); cv.q.y = pk2(u.z, u.w);
        cv.q.z = pk2(v.x, v.y); cv.q.w = pk2(v.z, v.w);
        a0 = cv.b;
      }
      if (r1 < N) {
        const float* p = &X[(long)r1 * K + kb];
        float4 u = *(const float4*)p, v = *(const float4*)(p + 4);
        union { uint4 q; bf16x8 b; } cv;
        cv.q.x = pk2(u.x, u.y); cv.q.y = pk2(u.z, u.w);
        cv.q.z = pk2(v.x, v.y); cv.q.w = pk2(v.z, v.w);
        a1 = cv.b;
      }
    } else if (kb < K) {  // partial tail (k=256..259)
      float t0[8], t1[8];
#pragma unroll
      for (int j = 0; j < 8; ++j) {
        int k = kb + j;
        t0[j] = (r0 < N && k < K) ? X[(long)r0 * K + k] : 0.f;
        t1[j] = (r1 < N && k < K) ? X[(long)r1 * K + k] : 0.f;
      }
      union { uint4 q; bf16x8 b; } c0, c1;
      c0.q.x = pk2(t0[0], t0[1]); c0.q.y = pk2(t0[2], t0[3]);
      c0.q.z = pk2(t0[4], t0[5]); c0.q.w = pk2(t0[6], t0[7]);
      c1.q.x = pk2(t1[0], t1[1]); c1.q.y = pk2(t1[2], t1[3]);
      c1.q.z = pk2(t1[4], t1[5]); c1.q.w = pk2(t1[6], t1[7]);
      a0 = c0.b; a1 = c1.b;
    } // else: fully past K -> zeros
    int ko = kt * 16 + kg * 4;
#pragma unroll
    for (int f = 0; f < 8; ++f) {
      bf16x8 b = *(const bf16x8*)&Wt[(f * 16 + lr) * 144 + ko];
      acc[0][f] = __builtin_amdgcn_mfma_f32_16x16x32_bf16(a0, b, acc[0][f], 0, 0, 0);
      acc[1][f] = __builtin_amdgcn_mfma_f32_16x16x32_bf16(a1, b, acc[1][f], 0, 0, 0);
    }
  }
#pragma unroll
  for (int rt = 0; rt < 2; ++rt) {
#pragma unroll
    for (int reg = 0; reg < 4; ++reg) {
      int row = wr0 + rt * 16 + kg * 4 + reg;
      float ds = (row < N) ? dscale[row] : 0.f;
#pragma unroll
      for (int f = 0; f < 8; ++f) {
        float v = acc[rt][f][reg] * ds;
        float pv = __shfl_xor(v, 1);
        if (!(l & 1) && row < N)
          Cu[(long)row * 64 + ((f * 16 + lr) >> 1)] = pk2(v, pv);
      }
    }
  }
}

// ---------------- pull aggregation + bias + relu (bf16 rows) ----------------
__global__ __launch_bounds__(256) void k_agg(const uint2* __restrict__ T,   // [N][32]
                                             const float* __restrict__ dinv,
                                             const int* __restrict__ rowstart,
                                             const int* __restrict__ deg,
                                             const int* __restrict__ csr,
                                             const float* __restrict__ bias,
                                             unsigned* __restrict__ outu,   // [N][64]
                                             int N) {
  __shared__ float sh[8][128];
  int i = blockIdx.x;
  int t = threadIdx.x;
  int g = t >> 5;
  int lane = t & 31;

  float4 acc = make_float4(0.f, 0.f, 0.f, 0.f);
  if (g == 0) {
    uint2 u = T[(long)i * 32 + lane];  // self-loop (pre-scaled by dinv)
    acc.x = blo(u.x); acc.y = bhi(u.x); acc.z = blo(u.y); acc.w = bhi(u.y);
  }

  int s0 = rowstart[i];
  int d = deg[i];
  int j = g;
  for (; j + 8 < d; j += 16) {
    int s1 = csr[s0 + j];
    int s2 = csr[s0 + j + 8];
    uint2 u1 = T[(long)s1 * 32 + lane];
    uint2 u2 = T[(long)s2 * 32 + lane];
    acc.x += blo(u1.x) + blo(u2.x);
    acc.y += bhi(u1.x) + bhi(u2.x);
    acc.z += blo(u1.y) + blo(u2.y);
    acc.w += bhi(u1.y) + bhi(u2.y);
  }
  if (j < d) {
    int s1 = csr[s0 + j];
    uint2 u1 = T[(long)s1 * 32 + lane];
    acc.x += blo(u1.x); acc.y += bhi(u1.x); acc.z += blo(u1.y); acc.w += bhi(u1.y);
  }
  *(float4*)&sh[g][lane * 4] = acc;
  __syncthreads();
  if (t < 128) {
    float total = 0.f;
#pragma unroll
    for (int gg = 0; gg < 8; ++gg) total += sh[gg][t];
    float v = fmaxf(dinv[i] * total + bias[t], 0.f);
    float w = __shfl_xor(v, 1);
    if (!(t & 1)) outu[(long)i * 64 + (t >> 1)] = pk2(v, w);
  }
}

// ---------------- graph start offsets from sorted batch ----------------
__global__ void k_starts(const int* __restrict__ batch, int N, int* __restrict__ start) {
  int i = blockIdx.x * blockDim.x + threadIdx.x;
  int stride = gridDim.x * blockDim.x;
  for (; i < N; i += stride) {
    int g = batch[i];
    if (i == 0) {
      start[g] = 0;
    } else if (batch[i - 1] != g) {
      start[g] = i;
    }
  }
}

__global__ void k_fix_starts(int* __restrict__ start, int G, int N) {
  if (blockIdx.x == 0 && threadIdx.x == 0) {
    start[G] = N;
    for (int g = G - 1; g >= 0; --g)
      if (start[g] < 0) start[g] = start[g + 1];
  }
}

// ---------------- mean-pool partial sums (batch sorted, h bf16) ----------------
__global__ __launch_bounds__(128) void k_pool(const unsigned* __restrict__ hu, // [N][64]
                                              const int* __restrict__ batch,
                                              float* __restrict__ psum, int N) {
  __shared__ int bsh[POOL_CHUNK];
  int c = threadIdx.x;
  int start = blockIdx.x * POOL_CHUNK;
  int end = min(N, start + POOL_CHUNK);
  int len = end - start;
  if (len <= 0) return;
  for (int i = c; i < len; i += 128) bsh[i] = batch[start + i];
  __syncthreads();
  int cur = bsh[0];
  float acc = 0.f;
  int half = c >> 1;
  int odd = c & 1;
  for (int i = 0; i < len; ++i) {
    int g = bsh[i];
    if (g != cur) {
      atomicAdd(&psum[cur * HID + c], acc);
      acc = 0.f;
      cur = g;
    }
    unsigned u = hu[(long)(start + i) * 64 + half];
    acc += odd ? bhi(u) : blo(u);
  }
  atomicAdd(&psum[cur * HID + c], acc);
}

// ---------------- MLP head ----------------
__global__ __launch_bounds__(128) void k_head(const float* __restrict__ psum,
                                              const int* __restrict__ gstart,
                                              const float* __restrict__ fc1w,
                                              const float* __restrict__ fc1b,
                                              const float* __restrict__ fc2w,
                                              const float* __restrict__ fc2b,
                                              float* __restrict__ out, int G) {
  __shared__ float pooled[HID];
  __shared__ float z1[HID];
  int g = blockIdx.x;
  int c = threadIdx.x;
  float cn = fmaxf((float)(gstart[g + 1] - gstart[g]), 1.f);
  pooled[c] = psum[g * HID + c] / cn;
  __syncthreads();
  float a = fc1b[c];
#pragma unroll 8
  for (int k = 0; k < HID; ++k) a += pooled[k] * fc1w[k * HID + c];
  z1[c] = fmaxf(a, 0.f);
  __syncthreads();
  if (c < 16) {
    float o = fc2b[c];
#pragma unroll 8
    for (int k = 0; k < HID; ++k) o += z1[k] * fc2w[k * 16 + c];
    out[g * 16 + c] = o;
  }
}

extern "C" void kernel_launch(void* const* d_in, const int* in_sizes, int n_in,
                              void* d_out, int out_size, void* d_ws, size_t ws_size,
                              hipStream_t stream) {
  const float* x     = (const float*)d_in[0];
  const int*   ei    = (const int*)d_in[1];
  const int*   batch = (const int*)d_in[2];
  const float* w1    = (const float*)d_in[3];
  const float* b1    = (const float*)d_in[4];
  const float* w2    = (const float*)d_in[5];
  const float* b2    = (const float*)d_in[6];
  const float* w3    = (const float*)d_in[7];
  const float* b3    = (const float*)d_in[8];
  const float* fc1w  = (const float*)d_in[9];
  const float* fc1b  = (const float*)d_in[10];
  const float* fc2w  = (const float*)d_in[11];
  const float* fc2b  = (const float*)d_in[12];
  float* out = (float*)d_out;

  const int IN = in_sizes[3] / HID;   // 260
  const int N  = in_sizes[0] / IN;    // 100000
  const int E  = in_sizes[1] / 2;     // 3200000
  const int G  = out_size / 16;       // 64

  const int* srcp = ei;
  const int* dstp = ei + E;

  // ---- workspace carve ----
  char* wsp = (char*)d_ws;
  auto alloc = [&](size_t bytes) {
    char* p = wsp;
    wsp += (bytes + 255) & ~(size_t)255;
    return p;
  };
  int*   deg      = (int*)alloc((size_t)N * 4);
  int*   rowstart = (int*)alloc((size_t)N * 4);
  int*   bsum     = (int*)alloc(1024 * 4);
  int*   boff     = (int*)alloc(1024 * 4);
  int*   bhist    = (int*)alloc(NB * 4);
  int*   bstart   = (int*)alloc((NB + 1) * 4);
  int*   gcur     = (int*)alloc(NB * 4);
  int*   gstart   = (int*)alloc((size_t)(G + 1) * 4);
  float* dinv     = (float*)alloc((size_t)N * 4);
  float* psum     = (float*)alloc((size_t)G * HID * 4);
  unsigned* Wt1   = (unsigned*)alloc(128 * 144 * 4);
  unsigned* Wt2   = (unsigned*)alloc(128 * 64 * 4);
  unsigned* Wt3   = (unsigned*)alloc(128 * 64 * 4);
  int*   csr      = (int*)alloc((size_t)E * 4);
  unsigned* bufA  = (unsigned*)alloc((size_t)N * 64 * 4);  // bf16 [N][128] packed
  unsigned* bufB  = (unsigned*)alloc((size_t)N * 64 * 4);  // bf16 [N][128] packed
  // binned edge array (E x 8B = 25.6MB) aliases bufA; consumed before first GEMM.
  unsigned long long* binned = (unsigned long long*)bufA;

  // ---- init ----
  k_fill32<<<4, 256, 0, stream>>>((int*)psum, G * HID, 0);
  k_fill32<<<1, 128, 0, stream>>>(gstart, G + 1, -1);
  k_fill32<<<1, 256, 0, stream>>>(bhist, NB, 0);

  // ---- weight prep (transpose + bf16) ----
  k_prep_w<<<72, 256, 0, stream>>>(w1, Wt1, IN, 144);
  k_prep_w<<<32, 256, 0, stream>>>(w2, Wt2, HID, 64);
  k_prep_w<<<32, 256, 0, stream>>>(w3, Wt3, HID, 64);

  // ---- binned CSR build ----
  k_hist<<<512, 256, 0, stream>>>(dstp, E, N, bhist);
  k_bscan<<<1, 1, 0, stream>>>(bhist, bstart, gcur, E);
  k_scatter<<<512, 256, 0, stream>>>(srcp, dstp, E, N, binned, gcur);
  k_bdeg<<<NB, 256, 0, stream>>>(binned, bstart, N, deg);
  k_dinv<<<(N + 255) / 256, 256, 0, stream>>>(deg, dinv, N);

  int nb = (N + SCAN_CHUNK - 1) / SCAN_CHUNK;
  k_scan_block_sums<<<nb, 256, 0, stream>>>(deg, N, bsum);
  k_scan_offsets<<<1, 1, 0, stream>>>(bsum, nb, boff);
  k_scan_write<<<nb, 256, 0, stream>>>(deg, N, boff, rowstart);
  k_place<<<NB, 256, 0, stream>>>(binned, bstart, rowstart, N, csr);

  // ---- graph boundaries ----
  k_starts<<<256, 256, 0, stream>>>(batch, N, gstart);
  k_fix_starts<<<1, 1, 0, stream>>>(gstart, G, N);

  // ---- 3 GCN layers: MFMA GEMM (epilogue scales by dinv, packs bf16) + agg ----
  int gblocks = (N + 127) / 128;
  k_gemm1_mf<<<gblocks, 256, 0, stream>>>(x, Wt1, dinv, bufA, N, IN);
  k_agg<<<N, 256, 0, stream>>>((const uint2*)bufA, dinv, rowstart, deg, csr, b1, bufB, N);

  k_gemm_mf<<<gblocks, 256, 0, stream>>>(bufB, Wt2, dinv, bufA, N);
  k_agg<<<N, 256, 0, stream>>>((const uint2*)bufA, dinv, rowstart, deg, csr, b2, bufB, N);

  k_gemm_mf<<<gblocks, 256, 0, stream>>>(bufB, Wt3, dinv, bufA, N);
  k_agg<<<N, 256, 0, stream>>>((const uint2*)bufA, dinv, rowstart, deg, csr, b3, bufB, N);

  // ---- pool + head ----
  int pblocks = (N + POOL_CHUNK - 1) / POOL_CHUNK;
  k_pool<<<pblocks, 128, 0, stream>>>(bufB, batch, psum, N);
  k_head<<<G, 128, 0, stream>>>(psum, gstart, fc1w, fc1b, fc2w, fc2b, out, G);
}